// Round 17
// baseline (464.379 us; speedup 1.0000x reference)
//
#include <hip/hip_runtime.h>
#include <math.h>

#define B_ 4
#define L_ 2048
#define D_ 768
#define H_ 12
#define F_ 3072
#define KTOP 307
#define KPAD 320
#define LN_EPS 1e-5f

typedef unsigned int u32;
typedef unsigned short u16;
using bf16x8 = __attribute__((ext_vector_type(8))) short;
using f32x4  = __attribute__((ext_vector_type(4))) float;

#define AS1 __attribute__((address_space(1)))
#define AS3 __attribute__((address_space(3)))

__device__ __forceinline__ void gl16(const void* g, void* l) {
    __builtin_amdgcn_global_load_lds((const AS1 u32*)g, (AS3 u32*)l, 16, 0, 0);
}
// explicit drain of the global_load_lds queue before barriers
__device__ __forceinline__ void wait_vm0() {
    asm volatile("s_waitcnt vmcnt(0)" ::: "memory");
}
__device__ __forceinline__ u16 f2bf(float f) {
    u32 u = __float_as_uint(f);
    return (u16)((u + 0x7fff + ((u >> 16) & 1)) >> 16);
}
__device__ __forceinline__ float bf2f(u16 s) {
    return __uint_as_float(((u32)s) << 16);
}
// tanh-form GELU: ~8 VALU ops vs ~30 for erff; |err| <= ~1e-3 << bf16 quantization.
__device__ __forceinline__ float gelu_tanh(float v) {
    float u = v * v * v;
    float z = fmaf(u, 0.0713548163f, 1.59576912f * v);
    float s = __builtin_amdgcn_rcpf(1.0f + __expf(-z));
    return v * s;
}

// ---------------- block reduce (256 threads) ----------------
__device__ __forceinline__ float blk_reduce_sum(float v, float* red) {
    #pragma unroll
    for (int off = 32; off; off >>= 1) v += __shfl_xor(v, off, 64);
    __syncthreads();
    if ((threadIdx.x & 63) == 0) red[threadIdx.x >> 6] = v;
    __syncthreads();
    return red[0] + red[1] + red[2] + red[3];
}
// dual-value block reduce: one butterfly pass carries sum AND sumsq (R11:
// halves the LN reduce rounds — 2 barriers instead of 4, 6 shuffle pairs).
__device__ __forceinline__ void blk_reduce_sum2(
    float a, float b, float* red, float& oa, float& ob)
{
    #pragma unroll
    for (int off = 32; off; off >>= 1) {
        a += __shfl_xor(a, off, 64);
        b += __shfl_xor(b, off, 64);
    }
    __syncthreads();
    if ((threadIdx.x & 63) == 0) {
        int w = threadIdx.x >> 6;
        red[w] = a; red[4 + w] = b;
    }
    __syncthreads();
    oa = red[0] + red[1] + red[2] + red[3];
    ob = red[4] + red[5] + red[6] + red[7];
}

// ---------------- LN -> bf16 normed (+ optional fp32 router score) ----------------
// var = E[x^2] - mean^2 (fp32; cancellation error ~1e-7 << bf16 quantization)
template <bool SCORE>
__global__ __launch_bounds__(256) void ln_kernel(
    const float* __restrict__ x, const float* __restrict__ g,
    const float* __restrict__ be, const float* __restrict__ Wr,
    const float* __restrict__ brp, u16* __restrict__ outn,
    float* __restrict__ scores)
{
    __shared__ float red[8];
    const int t = blockIdx.x;
    const int tid = threadIdx.x;
    const float* xr = x + (size_t)t * D_;
    float v0 = xr[tid], v1 = xr[tid + 256], v2 = xr[tid + 512];
    float s1, s2;
    blk_reduce_sum2(v0 + v1 + v2,
                    fmaf(v0, v0, fmaf(v1, v1, v2 * v2)), red, s1, s2);
    float mean = s1 * (1.0f / 768.0f);
    float var  = fmaf(-mean, mean, s2 * (1.0f / 768.0f));
    float inv = 1.0f / sqrtf(fmaxf(var, 0.f) + LN_EPS);
    float n0 = (v0 - mean) * inv * g[tid] + be[tid];
    float n1 = (v1 - mean) * inv * g[tid + 256] + be[tid + 256];
    float n2 = (v2 - mean) * inv * g[tid + 512] + be[tid + 512];
    u16* orow = outn + (size_t)t * D_;
    orow[tid] = f2bf(n0); orow[tid + 256] = f2bf(n1); orow[tid + 512] = f2bf(n2);
    if (SCORE) {
        __syncthreads();
        float dot = blk_reduce_sum(n0 * Wr[tid] + n1 * Wr[tid + 256] + n2 * Wr[tid + 512], red);
        if (tid == 0) scores[t] = 1.0f / (1.0f + expf(-(dot + brp[0])));
    }
}

// ---------------- exact radix-select top-k (lowest KTOP scores) ----------------
// 1 block/batch, 1024 threads. u32 bit order == float order (scores > 0).
// Selection set identical to sorting composite keys (score_bits<<32)|index:
// all score<s*, plus lowest-index `want` among score==s*.
__global__ __launch_bounds__(1024) void topk_kernel(
    const float* __restrict__ scores, unsigned* __restrict__ mask,
    float* __restrict__ ssum, int* __restrict__ rowmap, int* __restrict__ inv)
{
    __shared__ u32 sb[L_];
    __shared__ u32 hist[256];
    __shared__ u32 wsum[16];
    __shared__ float redf[16];
    __shared__ u32 bcast[2];
    __shared__ u32 cnt_sel;
    const int b = blockIdx.x, tid = threadIdx.x;
    const int lane = tid & 63, wv = tid >> 6;

    if (tid == 0) cnt_sel = 0;
    float s0 = scores[b * L_ + tid];
    float s1 = scores[b * L_ + tid + 1024];
    sb[tid] = __float_as_uint(s0);
    sb[tid + 1024] = __float_as_uint(s1);
    float v = s0 + s1;
    #pragma unroll
    for (int o = 32; o; o >>= 1) v += __shfl_xor(v, o, 64);
    if (lane == 0) redf[wv] = v;
    __syncthreads();
    if (tid == 0) {
        float t = 0.f;
        #pragma unroll
        for (int w = 0; w < 16; w++) t += redf[w];
        ssum[b] = t;
    }

    u32 want = KTOP, prefix = 0;
    #pragma unroll
    for (int pass = 0; pass < 4; pass++) {
        const int shift = 24 - pass * 8;
        if (tid < 256) hist[tid] = 0;
        __syncthreads();
        u32 x0 = sb[tid], x1 = sb[tid + 1024];
        if (pass == 0 || (x0 >> (shift + 8)) == prefix) atomicAdd(&hist[(x0 >> shift) & 255], 1u);
        if (pass == 0 || (x1 >> (shift + 8)) == prefix) atomicAdd(&hist[(x1 >> shift) & 255], 1u);
        __syncthreads();
        u32 c = 0, inc = 0;
        if (tid < 256) {
            c = hist[tid];
            inc = c;
            #pragma unroll
            for (int o = 1; o < 64; o <<= 1) {
                u32 t = __shfl_up(inc, o, 64);
                if (lane >= o) inc += t;
            }
            if (lane == 63) wsum[wv] = inc;
        }
        __syncthreads();
        if (tid < 256) {
            u32 base = 0;
            #pragma unroll
            for (int w = 0; w < 4; w++) if (w < wv) base += wsum[w];
            u32 incl = base + inc;
            u32 excl = incl - c;
            if (excl < want && want <= incl) {
                bcast[0] = (u32)tid;
                bcast[1] = want - excl;
            }
        }
        __syncthreads();
        prefix = (prefix << 8) | bcast[0];
        want = bcast[1];
    }

    // tie-break among score==s* by lowest index: block prefix-scan of eq flags
    const u32 sstar = prefix;
    u32 a0 = sb[2 * tid], a1 = sb[2 * tid + 1];
    u32 e0 = (a0 == sstar) ? 1u : 0u, e1 = (a1 == sstar) ? 1u : 0u;
    u32 ps = e0 + e1, inc2 = ps;
    #pragma unroll
    for (int o = 1; o < 64; o <<= 1) {
        u32 t = __shfl_up(inc2, o, 64);
        if (lane >= o) inc2 += t;
    }
    __syncthreads();          // wsum reuse: ensure pass-3 readers done
    if (lane == 63) wsum[wv] = inc2;
    __syncthreads();
    u32 base = 0;
    #pragma unroll
    for (int w = 0; w < 16; w++) if (w < wv) base += wsum[w];
    u32 excl0 = base + inc2 - ps;   // eq-rank of position 2*tid
    {
        int i = 2 * tid;
        bool sel = (a0 < sstar) || (e0 && (excl0 < want));
        mask[b * L_ + i] = sel ? 1u : 0u;
        int invv = 0;
        if (sel) {
            u32 slot = atomicAdd(&cnt_sel, 1u);
            rowmap[b * KPAD + slot] = b * L_ + i;
            invv = b * KPAD + (int)slot;
        }
        inv[b * L_ + i] = invv;
    }
    {
        int i = 2 * tid + 1;
        u32 r1 = excl0 + e0;
        bool sel = (a1 < sstar) || (e1 && (r1 < want));
        mask[b * L_ + i] = sel ? 1u : 0u;
        int invv = 0;
        if (sel) {
            u32 slot = atomicAdd(&cnt_sel, 1u);
            rowmap[b * KPAD + slot] = b * L_ + i;
            invv = b * KPAD + (int)slot;
        }
        inv[b * L_ + i] = invv;
    }
    if (tid < KPAD - KTOP)
        rowmap[b * KPAD + KTOP + tid] = b * L_;   // padding rows: any valid token
}

// ---------------- pooled partials (R11: 64 L-chunks -> 256 blocks, was 32) ----------------
__global__ __launch_bounds__(256) void pooled_part(
    const float* __restrict__ scores, const u16* __restrict__ nb,
    float* __restrict__ parts)
{
    const int lc = blockIdx.x, b = blockIdx.y, tid = threadIdx.x;
    float a0 = 0.f, a1 = 0.f, a2 = 0.f;
    const int l0 = lc * 32;
    for (int l = l0; l < l0 + 32; l++) {
        float s = scores[b * L_ + l];
        const u16* row = nb + (size_t)(b * L_ + l) * D_;
        a0 += s * bf2f(row[tid]);
        a1 += s * bf2f(row[tid + 256]);
        a2 += s * bf2f(row[tid + 512]);
    }
    float* p = parts + (size_t)(lc * B_ + b) * D_;
    p[tid] = a0; p[tid + 256] = a1; p[tid + 512] = a2;
}

// ---------------- fused: pooled = (sum parts)/ssum; pWm = pooled @ Wm ----------------
// R11: 48 blocks (was 12): block = 64 n-cols x 4-way k-split + LDS reduce.
__global__ __launch_bounds__(256) void pooled_wm(
    const float* __restrict__ parts, const float* __restrict__ ssum,
    const float* __restrict__ Wm, float* __restrict__ pWm)
{
    __shared__ float pl[768];
    __shared__ float red2[4][64];
    const int b = blockIdx.y, n0 = blockIdx.x * 64, tid = threadIdx.x;
    float inv = 1.0f / (ssum[b] + 1e-6f);
    for (int d = tid; d < 768; d += 256) {
        float s = 0.f;
        #pragma unroll 8
        for (int lc = 0; lc < 64; lc++) s += parts[(size_t)(lc * B_ + b) * D_ + d];
        pl[d] = s * inv;
    }
    __syncthreads();
    const int nl = tid & 63, kq = tid >> 6;
    const int n = n0 + nl;
    float acc = 0.f;
    const int k0 = kq * 192;
    for (int k = k0; k < k0 + 192; k++)
        acc = fmaf(pl[k], Wm[(size_t)k * D_ + n], acc);
    red2[kq][nl] = acc;
    __syncthreads();
    if (kq == 0)
        pWm[b * D_ + n] = red2[0][nl] + red2[1][nl] + red2[2][nl] + red2[3][nl];
}

// ---------------- fused weight convert+transpose (7 weights + biases, 1 launch) ----------------
__global__ __launch_bounds__(256) void wconv_all(
    const float* __restrict__ Wq, const float* __restrict__ Wk,
    const float* __restrict__ Wv, const float* __restrict__ Wo,
    const float* __restrict__ Wm, const float* __restrict__ W1,
    const float* __restrict__ W2,
    u16* __restrict__ WqT, u16* __restrict__ WkvT, u16* __restrict__ WoT,
    u16* __restrict__ WmT, u16* __restrict__ W1T, u16* __restrict__ W2T,
    const float* __restrict__ bq, const float* __restrict__ bk,
    const float* __restrict__ bv, float* __restrict__ bqs,
    float* __restrict__ bkv)
{
    __shared__ float t[32][33];
    int id = blockIdx.x;
    const int tid = threadIdx.x;
    if (id >= 7488) {   // bias-prep block
        for (int i = tid; i < 768; i += 256) {
            bqs[i] = bq[i] * 0.125f;
            bkv[i] = bk[i];
            bkv[768 + i] = bv[i];
        }
        return;
    }
    const float* src; u16* dst; int K, N, local; float sc = 1.f;
    if (id < 576)       { src = Wq; dst = WqT; K = 768; N = 768; local = id; sc = 0.125f; }
    else if (id < 1152) { src = Wk; dst = WkvT;            K = 768; N = 768; local = id - 576; }
    else if (id < 1728) { src = Wv; dst = WkvT + 768 * 768; K = 768; N = 768; local = id - 1152; }
    else if (id < 2304) { src = Wo; dst = WoT; K = 768; N = 768; local = id - 1728; }
    else if (id < 2880) { src = Wm; dst = WmT; K = 768; N = 768; local = id - 2304; }
    else if (id < 5184) { src = W1; dst = W1T; K = 768; N = 3072; local = id - 2880; }
    else                { src = W2; dst = W2T; K = 3072; N = 768; local = id - 5184; }
    const int ntiles = N >> 5;
    const int n0 = (local % ntiles) * 32, k0 = (local / ntiles) * 32;
    const int tx = tid & 31, ty = tid >> 5;
    #pragma unroll
    for (int i = 0; i < 4; i++)
        t[ty + i * 8][tx] = src[(size_t)(k0 + ty + i * 8) * N + n0 + tx];
    __syncthreads();
    #pragma unroll
    for (int i = 0; i < 4; i++)
        dst[(size_t)(n0 + ty + i * 8) * K + k0 + tx] = f2bf(t[tx][ty + i * 8] * sc);
}

// ---------------- bf16 MFMA GEMM: C = epi(A[M][K] @ WT[N][K]^T + bias) ----------------
// EPI: 0 fp32, 1 bf16, 2 gelu->bf16, 3 merge->h fp32, 4 +hres fp32
// RMAP: A row gathered through rowmap[]
// TM: 128 (4 waves 2x2, 64x64 each) or 64 (4 waves 1x4, 64x32 each); TN fixed 128.
// R15: counted-vmcnt ring pipeline (T4). K-step halved to 32; 4 LDS buffers
// at the SAME total LDS (64KB/48KB -> occupancy unchanged: 2 or 3 blocks/CU).
// 3 stages in flight; s_waitcnt vmcnt(2S) per phase (never 0 in steady state),
// raw s_barrier (NOT __syncthreads — that would re-drain vmcnt to 0).
// Ring hazards: buf b written by stage(t) issued after barrier of iter t-3;
// last reader compute(t-4) finished before that barrier.
// R14 history: TM=64-for-FFN1 (occupancy) was flat-MfmaUtil -> latency is
// the constraint; this attacks it directly.
template <int EPI, bool RMAP, int TM>
__global__ __launch_bounds__(256) void mfma_gemm(
    const u16* __restrict__ A, const u16* __restrict__ Bt,
    const float* __restrict__ bias, void* __restrict__ Cout,
    int N, int K, int nbn,
    const float* __restrict__ x, const unsigned* __restrict__ msk,
    const float* __restrict__ attn, const float* __restrict__ scores,
    const float* __restrict__ pWm, const float* __restrict__ hres,
    const int* __restrict__ rowmap, const int* __restrict__ invmap)
{
    constexpr int NI = (TM == 128) ? 4 : 2;
    constexpr int AL = TM / 64;            // A gl16s per stage per thread (2 or 1)
    __shared__ u16 Asm[4][TM * 32];
    __shared__ u16 Bsm[4][128 * 32];
    const int tid = threadIdx.x;
    const int wave = tid >> 6, lane = tid & 63;
    const int quad = lane >> 4, l15 = lane & 15;

    const int nwg = gridDim.x;
    const int bid = blockIdx.x;
    // bijective only when nwg%8==0 (all GEMM grids here: 768/120/1536)
    const int wid = ((nwg & 7) == 0) ? ((bid & 7) * (nwg >> 3) + (bid >> 3)) : bid;
    const int m0 = (wid / nbn) * TM, n0 = (wid % nbn) * 128;
    const int wm = (TM == 128) ? (wave >> 1) * 64 : 0;
    const int wn = (TM == 128) ? (wave & 1) * 64 : wave * 32;

    f32x4 acc[4][NI];
    #pragma unroll
    for (int i = 0; i < 4; i++)
        #pragma unroll
        for (int j = 0; j < NI; j++) acc[i][j] = 0.f;

    // slot s in [0, TM*4): row = s>>2, chunk c = s&3, swizzled cs = c ^ (row&3)
    const u16* ap[AL]; const u16* bp[2];
    #pragma unroll
    for (int i = 0; i < AL; i++) {
        int s = i * 256 + tid;
        int row = s >> 2;
        int cs = (s & 3) ^ (row & 3);
        int arow = RMAP ? rowmap[m0 + row] : (m0 + row);
        ap[i] = A + (size_t)arow * K + cs * 8;
    }
    #pragma unroll
    for (int i = 0; i < 2; i++) {
        int s = i * 256 + tid;
        int row = s >> 2;
        int cs = (s & 3) ^ (row & 3);
        bp[i] = Bt + (size_t)(n0 + row) * K + cs * 8;
    }

    // stage one 32-wide K-subtile into ring buffer `buf`, advance pointers
    auto stage = [&](int buf) {
        #pragma unroll
        for (int i = 0; i < AL; i++) {
            gl16(ap[i], &Asm[buf][(i * 256 + wave * 64) * 8]);
            ap[i] += 32;
        }
        #pragma unroll
        for (int i = 0; i < 2; i++) {
            gl16(bp[i], &Bsm[buf][(i * 256 + wave * 64) * 8]);
            bp[i] += 32;
        }
    };
    // MFMA over one 32-wide subtile
    auto compute = [&](int buf) {
        bf16x8 af[4], bfr[NI];
        #pragma unroll
        for (int mi = 0; mi < 4; mi++) {
            int row = wm + mi * 16 + l15;
            af[mi] = *(const bf16x8*)&Asm[buf][(row * 4 + (quad ^ (row & 3))) * 8];
        }
        #pragma unroll
        for (int ni = 0; ni < NI; ni++) {
            int row = wn + ni * 16 + l15;
            bfr[ni] = *(const bf16x8*)&Bsm[buf][(row * 4 + (quad ^ (row & 3))) * 8];
        }
        #pragma unroll
        for (int mi = 0; mi < 4; mi++)
            #pragma unroll
            for (int ni = 0; ni < NI; ni++)
                acc[mi][ni] = __builtin_amdgcn_mfma_f32_16x16x32_bf16(
                    af[mi], bfr[ni], acc[mi][ni], 0, 0, 0);
    };

    const int nt = K >> 5;          // 24 or 96 here: always >= 3
    stage(0); stage(1); stage(2);   // 3 stages in flight
    for (int t = 0; t < nt; t++) {
        // wait for stage(t) only: leave the younger stages' loads in flight
        if (t < nt - 2) {
            if constexpr (TM == 128) asm volatile("s_waitcnt vmcnt(8)" ::: "memory");
            else                     asm volatile("s_waitcnt vmcnt(6)" ::: "memory");
        } else if (t == nt - 2) {
            if constexpr (TM == 128) asm volatile("s_waitcnt vmcnt(4)" ::: "memory");
            else                     asm volatile("s_waitcnt vmcnt(3)" ::: "memory");
        } else {
            asm volatile("s_waitcnt vmcnt(0)" ::: "memory");
        }
        __builtin_amdgcn_s_barrier();
        if (t + 3 < nt) stage((t + 3) & 3);
        compute(t & 3);
    }

    #pragma unroll
    for (int mi = 0; mi < 4; mi++) {
        #pragma unroll
        for (int ni = 0; ni < NI; ni++) {
            #pragma unroll
            for (int r = 0; r < 4; r++) {
                int row = m0 + wm + mi * 16 + quad * 4 + r;
                int col = n0 + wn + ni * 16 + l15;
                float v = acc[mi][ni][r] + bias[col];
                size_t off = (size_t)row * N + col;
                if (EPI == 0) ((float*)Cout)[off] = v;
                else if (EPI == 1) ((u16*)Cout)[off] = f2bf(v);
                else if (EPI == 2) ((u16*)Cout)[off] = f2bf(gelu_tanh(v));
                else if (EPI == 3) {
                    float mix = v + scores[row] * pWm[(row >> 11) * D_ + col];
                    float sel = msk[row] ? attn[(size_t)invmap[row] * D_ + col] : mix;
                    ((float*)Cout)[off] = x[off] + sel;
                } else {
                    ((float*)Cout)[off] = v + hres[off];
                }
            }
        }
    }
}

// ---------------- V transpose: V[token][ld slice] -> VT[(b*H+h)*64+d][L] ----------------
__global__ __launch_bounds__(256) void vtrans(
    const u16* __restrict__ V, u16* __restrict__ VT, int ld)
{
    __shared__ u16 tl[64 * 72];
    const int tid = threadIdx.x;
    const int l0 = blockIdx.x * 64, h = blockIdx.y, b = blockIdx.z;
    const u16* src = V + h * 64;
    {
        int r = tid >> 3, ch = tid & 7;
        *(uint4*)&tl[r * 72 + ch * 8] =
            *(const uint4*)&src[(size_t)(b * L_ + l0 + r) * ld + ch * 8];
        int t2 = tid + 256; r = t2 >> 3; ch = t2 & 7;
        *(uint4*)&tl[r * 72 + ch * 8] =
            *(const uint4*)&src[(size_t)(b * L_ + l0 + r) * ld + ch * 8];
    }
    __syncthreads();
    int d = tid >> 2, lg = (tid & 3) * 16;
    u16* dst = VT + (size_t)((b * H_ + h) * 64 + d) * L_ + l0 + lg;
    union { u16 s[8]; uint4 v; } pk;
    #pragma unroll
    for (int j = 0; j < 8; j++) pk.s[j] = tl[(lg + j) * 72 + d];
    *(uint4*)dst = pk.v;
    #pragma unroll
    for (int j = 0; j < 8; j++) pk.s[j] = tl[(lg + 8 + j) * 72 + d];
    *(uint4*)(dst + 8) = pk.v;
}

// ---------------- compacted-Q MFMA attention, fixed-shift softmax ----------------
// R14: K/V double-buffered (2-phase): attn2 runs 240 blocks < 256 CUs ->
// 1 block/CU, zero TLP; prefetch tile t+1 under compute of t.
__global__ __launch_bounds__(256) void attn2(
    const u16* __restrict__ qcomp, const u16* __restrict__ Kg,
    const u16* __restrict__ VTg, u16* __restrict__ ctxc)
{
    __shared__ u16 Qs[64 * 64];
    __shared__ u16 Ks[2][64 * 64];
    __shared__ u16 Vs[2][64 * 64];
    __shared__ u16 Ps[4 * 16 * 72];
    const int tid = threadIdx.x, wave = tid >> 6, lane = tid & 63;
    const int quad = lane >> 4, l15 = lane & 15;
    const int qb = blockIdx.x, h = blockIdx.y, b = blockIdx.z;
    const int q0 = qb * 64;

    {
        int s0 = wave * 64 + lane;
        int r = s0 >> 3, c = (s0 & 7) ^ (r & 7);
        gl16(qcomp + (size_t)(b * KPAD + q0 + r) * D_ + h * 64 + c * 8,
             &Qs[(wave * 64) * 8]);
        int s1 = s0 + 256;
        int r1 = s1 >> 3, c1 = (s1 & 7) ^ (r1 & 7);
        gl16(qcomp + (size_t)(b * KPAD + q0 + r1) * D_ + h * 64 + c1 * 8,
             &Qs[(256 + wave * 64) * 8]);
    }
    const u16 *kp0, *kp1, *vp0, *vp1;
    {
        int s0 = wave * 64 + lane;
        int r = s0 >> 3, c = (s0 & 7) ^ (r & 7);
        kp0 = Kg + (size_t)(b * L_ + r) * 1536 + h * 64 + c * 8;
        vp0 = VTg + (size_t)((b * H_ + h) * 64 + r) * L_ + c * 8;
        int s1 = s0 + 256;
        int r1 = s1 >> 3, c1 = (s1 & 7) ^ (r1 & 7);
        kp1 = Kg + (size_t)(b * L_ + r1) * 1536 + h * 64 + c1 * 8;
        vp1 = VTg + (size_t)((b * H_ + h) * 64 + r1) * L_ + c1 * 8;
    }
    // prologue: stage K/V tile 0 into buf 0 (alongside the Q stage above)
    gl16(kp0, &Ks[0][(wave * 64) * 8]);        kp0 += (size_t)64 * 1536;
    gl16(kp1, &Ks[0][(256 + wave * 64) * 8]);  kp1 += (size_t)64 * 1536;
    gl16(vp0, &Vs[0][(wave * 64) * 8]);        vp0 += 64;
    gl16(vp1, &Vs[0][(256 + wave * 64) * 8]);  vp1 += 64;
    wait_vm0();
    __syncthreads();
    bf16x8 qf0, qf1;
    {
        int row = wave * 16 + l15;
        qf0 = *(const bf16x8*)&Qs[(row * 8 + ((quad)     ^ (row & 7))) * 8];
        qf1 = *(const bf16x8*)&Qs[(row * 8 + ((4 + quad) ^ (row & 7))) * 8];
    }
    f32x4 accO[4]; float lp[4];
    #pragma unroll
    for (int i = 0; i < 4; i++) { accO[i] = 0.f; lp[i] = 0.f; }
    u16* Psw = Ps + wave * 16 * 72;

    for (int kt = 0; kt < L_; kt += 64) {
        const int buf = (kt >> 6) & 1;
        if (kt + 64 < L_) {         // prefetch tile t+1 into the other buffer
            gl16(kp0, &Ks[buf ^ 1][(wave * 64) * 8]);        kp0 += (size_t)64 * 1536;
            gl16(kp1, &Ks[buf ^ 1][(256 + wave * 64) * 8]);  kp1 += (size_t)64 * 1536;
            gl16(vp0, &Vs[buf ^ 1][(wave * 64) * 8]);        vp0 += 64;
            gl16(vp1, &Vs[buf ^ 1][(256 + wave * 64) * 8]);  vp1 += 64;
        }

        f32x4 accS[4];
        #pragma unroll
        for (int ni = 0; ni < 4; ni++) accS[ni] = 0.f;
        #pragma unroll
        for (int kk = 0; kk < 2; kk++) {
            const int kq = kk * 4 + quad;
            #pragma unroll
            for (int ni = 0; ni < 4; ni++) {
                int row = ni * 16 + l15;
                bf16x8 kf = *(const bf16x8*)&Ks[buf][(row * 8 + (kq ^ (row & 7))) * 8];
                accS[ni] = __builtin_amdgcn_mfma_f32_16x16x32_bf16(
                    kk ? qf1 : qf0, kf, accS[ni], 0, 0, 0);
            }
        }
        #pragma unroll
        for (int ni = 0; ni < 4; ni++) {
            #pragma unroll
            for (int r = 0; r < 4; r++) {
                float p = __expf(accS[ni][r]);
                lp[r] += p;
                Psw[(quad * 4 + r) * 72 + ni * 16 + l15] = f2bf(p);
            }
        }
        #pragma unroll
        for (int kk = 0; kk < 2; kk++) {
            bf16x8 pf = *(const bf16x8*)&Psw[l15 * 72 + kk * 32 + quad * 8];
            const int kq = kk * 4 + quad;
            #pragma unroll
            for (int ni = 0; ni < 4; ni++) {
                int row = ni * 16 + l15;
                bf16x8 vf = *(const bf16x8*)&Vs[buf][(row * 8 + (kq ^ (row & 7))) * 8];
                accO[ni] = __builtin_amdgcn_mfma_f32_16x16x32_bf16(pf, vf, accO[ni], 0, 0, 0);
            }
        }
        wait_vm0();                 // prefetch landed; barrier guards buf swap
        __syncthreads();
    }

    float invl[4];
    #pragma unroll
    for (int r = 0; r < 4; r++) {
        float s = lp[r];
        s += __shfl_xor(s, 1, 64); s += __shfl_xor(s, 2, 64);
        s += __shfl_xor(s, 4, 64); s += __shfl_xor(s, 8, 64);
        invl[r] = 1.0f / s;
    }
    #pragma unroll
    for (int ni = 0; ni < 4; ni++) {
        #pragma unroll
        for (int r = 0; r < 4; r++) {
            int ql = q0 + wave * 16 + quad * 4 + r;
            if (ql < KTOP)
                ctxc[(size_t)(b * KPAD + ql) * D_ + h * 64 + ni * 16 + l15] =
                    f2bf(accO[ni][r] * invl[r]);
        }
    }
}

// ---------------- launch ----------------
extern "C" void kernel_launch(void* const* d_in, const int* in_sizes, int n_in,
                              void* d_out, int out_size, void* d_ws, size_t ws_size,
                              hipStream_t stream)
{
    const float* x   = (const float*)d_in[0];
    const float* g1  = (const float*)d_in[1];
    const float* b1  = (const float*)d_in[2];
    const float* g2  = (const float*)d_in[3];
    const float* b2  = (const float*)d_in[4];
    const float* Wr  = (const float*)d_in[5];
    const float* br  = (const float*)d_in[6];
    const float* Wq  = (const float*)d_in[7];
    const float* bq  = (const float*)d_in[8];
    const float* Wk  = (const float*)d_in[9];
    const float* bk  = (const float*)d_in[10];
    const float* Wv  = (const float*)d_in[11];
    const float* bv  = (const float*)d_in[12];
    const float* Wo  = (const float*)d_in[13];
    const float* bo  = (const float*)d_in[14];
    const float* Wm  = (const float*)d_in[15];
    const float* bm  = (const float*)d_in[16];
    const float* W1  = (const float*)d_in[17];
    const float* bf1 = (const float*)d_in[18];
    const float* W2  = (const float*)d_in[19];
    const float* bf2 = (const float*)d_in[20];
    float* out = (float*)d_out;

    char* W = (char*)d_ws;
    u16* WqT  = (u16*)(W + 0);
    u16* WkvT = (u16*)(W + 1179648);
    u16* WoT  = (u16*)(W + 3538944);
    u16* WmT  = (u16*)(W + 4718592);
    u16* W1T  = (u16*)(W + 5898240);
    u16* W2T  = (u16*)(W + 10616832);
    float* scores  = (float*)(W + 15335424);
    unsigned* mask = (unsigned*)(W + 15368192);
    float* ssum    = (float*)(W + 15400960);
    float* pWm     = (float*)(W + 15413504);
    float* bkv     = (float*)(W + 15524096);
    float* bqs     = (float*)(W + 15530240);
    int* rowmap    = (int*)(W + 15533312);
    int* invmap    = (int*)(W + 15538432);
    u16* nb    = (u16*)(W + 15728640);
    u16* Y     = (u16*)(W + 28311552);
    u16* qcomp = (u16*)(W + 53477376);
    u16* ctxc  = (u16*)(W + 55443456);
    float* attnc = (float*)(W + 57409536);
    u16* VT    = (u16*)(W + 61341696);
    float* h   = (float*)(W + 28311552);
    u16* n2b   = (u16*)(W + 15728640);
    u16* mid   = (u16*)(W + 53477376);
    // R11: parts grew to 64 chunks x B x D fp32 (786KB) — aliases the qcomp
    // region, which is dead until the Q-projection (pooled_* run before it).
    float* parts = (float*)(W + 53477376);

    wconv_all<<<7489, 256, 0, stream>>>(Wq, Wk, Wv, Wo, Wm, W1, W2,
                                        WqT, WkvT, WoT, WmT, W1T, W2T,
                                        bq, bk, bv, bqs, bkv);

    const int NT = B_ * L_;
    ln_kernel<true><<<NT, 256, 0, stream>>>(x, g1, b1, Wr, br, nb, scores);
    topk_kernel<<<B_, 1024, 0, stream>>>(scores, mask, ssum, rowmap, invmap);
    pooled_part<<<dim3(64, B_), 256, 0, stream>>>(scores, nb, parts);
    pooled_wm<<<dim3(12, B_), 256, 0, stream>>>(parts, ssum, Wm, pWm);

    // dense KV projection -> Y [8192][1536]  (64 m x 12 n = 768 blocks)
    mfma_gemm<1, false, 128><<<768, 256, 0, stream>>>(nb, WkvT, bkv, Y, 1536, 768, 12,
        nullptr, nullptr, nullptr, nullptr, nullptr, nullptr, nullptr, nullptr);
    // gathered Q projection (scaled 1/8) -> qcomp [1280][768]  (20 m x 6 n = 120)
    mfma_gemm<1, true, 64><<<120, 256, 0, stream>>>(nb, WqT, bqs, qcomp, 768, 768, 6,
        nullptr, nullptr, nullptr, nullptr, nullptr, nullptr, rowmap, nullptr);
    // V transpose -> VT
    vtrans<<<dim3(32, H_, B_), 256, 0, stream>>>(Y + 768, VT, 1536);
    // compacted attention -> ctxc
    attn2<<<dim3(KPAD / 64, H_, B_), 256, 0, stream>>>(qcomp, Y, VT, ctxc);
    // attn_out (compact) = ctxc @ Wo + bo  (20 m x 6 n = 120)
    mfma_gemm<0, false, 64><<<120, 256, 0, stream>>>(ctxc, WoT, bo, attnc, 768, 768, 6,
        nullptr, nullptr, nullptr, nullptr, nullptr, nullptr, nullptr, nullptr);
    // h = x + where(mask, attnc[inv], normed@Wm + bm + s*pWm)  (128 m x 6 n = 768)
    mfma_gemm<3, false, 64><<<768, 256, 0, stream>>>(nb, WmT, bm, h, 768, 768, 6,
        x, mask, attnc, scores, pWm, nullptr, nullptr, invmap);
    // LN2 -> n2b
    ln_kernel<false><<<NT, 256, 0, stream>>>(h, g2, b2, nullptr, nullptr, n2b, nullptr);
    // FFN1 (TM=128, 64 m x 24 n = 1536 blocks)
    mfma_gemm<2, false, 128><<<1536, 256, 0, stream>>>(n2b, W1T, bf1, mid, 3072, 768, 24,
        nullptr, nullptr, nullptr, nullptr, nullptr, nullptr, nullptr, nullptr);
    // FFN2 (128 m x 6 n = 768)
    mfma_gemm<4, false, 64><<<768, 256, 0, stream>>>(mid, W2T, bf2, out, 768, 3072, 6,
        nullptr, nullptr, nullptr, nullptr, nullptr, h, nullptr, nullptr);
}

// Round 18
// 460.662 us; speedup vs baseline: 1.0081x; 1.0081x over previous
//
#include <hip/hip_runtime.h>
#include <math.h>

#define B_ 4
#define L_ 2048
#define D_ 768
#define H_ 12
#define F_ 3072
#define KTOP 307
#define KPAD 320
#define LN_EPS 1e-5f

typedef unsigned int u32;
typedef unsigned short u16;
using bf16x8 = __attribute__((ext_vector_type(8))) short;
using f32x4  = __attribute__((ext_vector_type(4))) float;

#define AS1 __attribute__((address_space(1)))
#define AS3 __attribute__((address_space(3)))

__device__ __forceinline__ void gl16(const void* g, void* l) {
    __builtin_amdgcn_global_load_lds((const AS1 u32*)g, (AS3 u32*)l, 16, 0, 0);
}
// explicit drain of the global_load_lds queue before barriers
__device__ __forceinline__ void wait_vm0() {
    asm volatile("s_waitcnt vmcnt(0)" ::: "memory");
}
__device__ __forceinline__ u16 f2bf(float f) {
    u32 u = __float_as_uint(f);
    return (u16)((u + 0x7fff + ((u >> 16) & 1)) >> 16);
}
__device__ __forceinline__ float bf2f(u16 s) {
    return __uint_as_float(((u32)s) << 16);
}
// tanh-form GELU: ~8 VALU ops vs ~30 for erff; |err| <= ~1e-3 << bf16 quantization.
__device__ __forceinline__ float gelu_tanh(float v) {
    float u = v * v * v;
    float z = fmaf(u, 0.0713548163f, 1.59576912f * v);
    float s = __builtin_amdgcn_rcpf(1.0f + __expf(-z));
    return v * s;
}

// ---------------- block reduce (256 threads) ----------------
__device__ __forceinline__ float blk_reduce_sum(float v, float* red) {
    #pragma unroll
    for (int off = 32; off; off >>= 1) v += __shfl_xor(v, off, 64);
    __syncthreads();
    if ((threadIdx.x & 63) == 0) red[threadIdx.x >> 6] = v;
    __syncthreads();
    return red[0] + red[1] + red[2] + red[3];
}
// dual-value block reduce: one butterfly pass carries sum AND sumsq (R11:
// halves the LN reduce rounds — 2 barriers instead of 4, 6 shuffle pairs).
__device__ __forceinline__ void blk_reduce_sum2(
    float a, float b, float* red, float& oa, float& ob)
{
    #pragma unroll
    for (int off = 32; off; off >>= 1) {
        a += __shfl_xor(a, off, 64);
        b += __shfl_xor(b, off, 64);
    }
    __syncthreads();
    if ((threadIdx.x & 63) == 0) {
        int w = threadIdx.x >> 6;
        red[w] = a; red[4 + w] = b;
    }
    __syncthreads();
    oa = red[0] + red[1] + red[2] + red[3];
    ob = red[4] + red[5] + red[6] + red[7];
}

// ---------------- LN -> bf16 normed (+ optional fp32 router score) ----------------
// var = E[x^2] - mean^2 (fp32; cancellation error ~1e-7 << bf16 quantization)
template <bool SCORE>
__global__ __launch_bounds__(256) void ln_kernel(
    const float* __restrict__ x, const float* __restrict__ g,
    const float* __restrict__ be, const float* __restrict__ Wr,
    const float* __restrict__ brp, u16* __restrict__ outn,
    float* __restrict__ scores)
{
    __shared__ float red[8];
    const int t = blockIdx.x;
    const int tid = threadIdx.x;
    const float* xr = x + (size_t)t * D_;
    float v0 = xr[tid], v1 = xr[tid + 256], v2 = xr[tid + 512];
    float s1, s2;
    blk_reduce_sum2(v0 + v1 + v2,
                    fmaf(v0, v0, fmaf(v1, v1, v2 * v2)), red, s1, s2);
    float mean = s1 * (1.0f / 768.0f);
    float var  = fmaf(-mean, mean, s2 * (1.0f / 768.0f));
    float inv = 1.0f / sqrtf(fmaxf(var, 0.f) + LN_EPS);
    float n0 = (v0 - mean) * inv * g[tid] + be[tid];
    float n1 = (v1 - mean) * inv * g[tid + 256] + be[tid + 256];
    float n2 = (v2 - mean) * inv * g[tid + 512] + be[tid + 512];
    u16* orow = outn + (size_t)t * D_;
    orow[tid] = f2bf(n0); orow[tid + 256] = f2bf(n1); orow[tid + 512] = f2bf(n2);
    if (SCORE) {
        __syncthreads();
        float dot = blk_reduce_sum(n0 * Wr[tid] + n1 * Wr[tid + 256] + n2 * Wr[tid + 512], red);
        if (tid == 0) scores[t] = 1.0f / (1.0f + expf(-(dot + brp[0])));
    }
}

// ---------------- exact radix-select top-k (lowest KTOP scores) ----------------
// 1 block/batch, 1024 threads. u32 bit order == float order (scores > 0).
// Selection set identical to sorting composite keys (score_bits<<32)|index:
// all score<s*, plus lowest-index `want` among score==s*.
__global__ __launch_bounds__(1024) void topk_kernel(
    const float* __restrict__ scores, unsigned* __restrict__ mask,
    float* __restrict__ ssum, int* __restrict__ rowmap, int* __restrict__ inv)
{
    __shared__ u32 sb[L_];
    __shared__ u32 hist[256];
    __shared__ u32 wsum[16];
    __shared__ float redf[16];
    __shared__ u32 bcast[2];
    __shared__ u32 cnt_sel;
    const int b = blockIdx.x, tid = threadIdx.x;
    const int lane = tid & 63, wv = tid >> 6;

    if (tid == 0) cnt_sel = 0;
    float s0 = scores[b * L_ + tid];
    float s1 = scores[b * L_ + tid + 1024];
    sb[tid] = __float_as_uint(s0);
    sb[tid + 1024] = __float_as_uint(s1);
    float v = s0 + s1;
    #pragma unroll
    for (int o = 32; o; o >>= 1) v += __shfl_xor(v, o, 64);
    if (lane == 0) redf[wv] = v;
    __syncthreads();
    if (tid == 0) {
        float t = 0.f;
        #pragma unroll
        for (int w = 0; w < 16; w++) t += redf[w];
        ssum[b] = t;
    }

    u32 want = KTOP, prefix = 0;
    #pragma unroll
    for (int pass = 0; pass < 4; pass++) {
        const int shift = 24 - pass * 8;
        if (tid < 256) hist[tid] = 0;
        __syncthreads();
        u32 x0 = sb[tid], x1 = sb[tid + 1024];
        if (pass == 0 || (x0 >> (shift + 8)) == prefix) atomicAdd(&hist[(x0 >> shift) & 255], 1u);
        if (pass == 0 || (x1 >> (shift + 8)) == prefix) atomicAdd(&hist[(x1 >> shift) & 255], 1u);
        __syncthreads();
        u32 c = 0, inc = 0;
        if (tid < 256) {
            c = hist[tid];
            inc = c;
            #pragma unroll
            for (int o = 1; o < 64; o <<= 1) {
                u32 t = __shfl_up(inc, o, 64);
                if (lane >= o) inc += t;
            }
            if (lane == 63) wsum[wv] = inc;
        }
        __syncthreads();
        if (tid < 256) {
            u32 base = 0;
            #pragma unroll
            for (int w = 0; w < 4; w++) if (w < wv) base += wsum[w];
            u32 incl = base + inc;
            u32 excl = incl - c;
            if (excl < want && want <= incl) {
                bcast[0] = (u32)tid;
                bcast[1] = want - excl;
            }
        }
        __syncthreads();
        prefix = (prefix << 8) | bcast[0];
        want = bcast[1];
    }

    // tie-break among score==s* by lowest index: block prefix-scan of eq flags
    const u32 sstar = prefix;
    u32 a0 = sb[2 * tid], a1 = sb[2 * tid + 1];
    u32 e0 = (a0 == sstar) ? 1u : 0u, e1 = (a1 == sstar) ? 1u : 0u;
    u32 ps = e0 + e1, inc2 = ps;
    #pragma unroll
    for (int o = 1; o < 64; o <<= 1) {
        u32 t = __shfl_up(inc2, o, 64);
        if (lane >= o) inc2 += t;
    }
    __syncthreads();          // wsum reuse: ensure pass-3 readers done
    if (lane == 63) wsum[wv] = inc2;
    __syncthreads();
    u32 base = 0;
    #pragma unroll
    for (int w = 0; w < 16; w++) if (w < wv) base += wsum[w];
    u32 excl0 = base + inc2 - ps;   // eq-rank of position 2*tid
    {
        int i = 2 * tid;
        bool sel = (a0 < sstar) || (e0 && (excl0 < want));
        mask[b * L_ + i] = sel ? 1u : 0u;
        int invv = 0;
        if (sel) {
            u32 slot = atomicAdd(&cnt_sel, 1u);
            rowmap[b * KPAD + slot] = b * L_ + i;
            invv = b * KPAD + (int)slot;
        }
        inv[b * L_ + i] = invv;
    }
    {
        int i = 2 * tid + 1;
        u32 r1 = excl0 + e0;
        bool sel = (a1 < sstar) || (e1 && (r1 < want));
        mask[b * L_ + i] = sel ? 1u : 0u;
        int invv = 0;
        if (sel) {
            u32 slot = atomicAdd(&cnt_sel, 1u);
            rowmap[b * KPAD + slot] = b * L_ + i;
            invv = b * KPAD + (int)slot;
        }
        inv[b * L_ + i] = invv;
    }
    if (tid < KPAD - KTOP)
        rowmap[b * KPAD + KTOP + tid] = b * L_;   // padding rows: any valid token
}

// ---------------- pooled partials (R11: 64 L-chunks -> 256 blocks, was 32) ----------------
__global__ __launch_bounds__(256) void pooled_part(
    const float* __restrict__ scores, const u16* __restrict__ nb,
    float* __restrict__ parts)
{
    const int lc = blockIdx.x, b = blockIdx.y, tid = threadIdx.x;
    float a0 = 0.f, a1 = 0.f, a2 = 0.f;
    const int l0 = lc * 32;
    for (int l = l0; l < l0 + 32; l++) {
        float s = scores[b * L_ + l];
        const u16* row = nb + (size_t)(b * L_ + l) * D_;
        a0 += s * bf2f(row[tid]);
        a1 += s * bf2f(row[tid + 256]);
        a2 += s * bf2f(row[tid + 512]);
    }
    float* p = parts + (size_t)(lc * B_ + b) * D_;
    p[tid] = a0; p[tid + 256] = a1; p[tid + 512] = a2;
}

// ---------------- fused: pooled = (sum parts)/ssum; pWm = pooled @ Wm ----------------
// R11: 48 blocks (was 12): block = 64 n-cols x 4-way k-split + LDS reduce.
__global__ __launch_bounds__(256) void pooled_wm(
    const float* __restrict__ parts, const float* __restrict__ ssum,
    const float* __restrict__ Wm, float* __restrict__ pWm)
{
    __shared__ float pl[768];
    __shared__ float red2[4][64];
    const int b = blockIdx.y, n0 = blockIdx.x * 64, tid = threadIdx.x;
    float inv = 1.0f / (ssum[b] + 1e-6f);
    for (int d = tid; d < 768; d += 256) {
        float s = 0.f;
        #pragma unroll 8
        for (int lc = 0; lc < 64; lc++) s += parts[(size_t)(lc * B_ + b) * D_ + d];
        pl[d] = s * inv;
    }
    __syncthreads();
    const int nl = tid & 63, kq = tid >> 6;
    const int n = n0 + nl;
    float acc = 0.f;
    const int k0 = kq * 192;
    for (int k = k0; k < k0 + 192; k++)
        acc = fmaf(pl[k], Wm[(size_t)k * D_ + n], acc);
    red2[kq][nl] = acc;
    __syncthreads();
    if (kq == 0)
        pWm[b * D_ + n] = red2[0][nl] + red2[1][nl] + red2[2][nl] + red2[3][nl];
}

// ---------------- fused weight convert+transpose (7 weights + biases, 1 launch) ----------------
__global__ __launch_bounds__(256) void wconv_all(
    const float* __restrict__ Wq, const float* __restrict__ Wk,
    const float* __restrict__ Wv, const float* __restrict__ Wo,
    const float* __restrict__ Wm, const float* __restrict__ W1,
    const float* __restrict__ W2,
    u16* __restrict__ WqT, u16* __restrict__ WkvT, u16* __restrict__ WoT,
    u16* __restrict__ WmT, u16* __restrict__ W1T, u16* __restrict__ W2T,
    const float* __restrict__ bq, const float* __restrict__ bk,
    const float* __restrict__ bv, float* __restrict__ bqs,
    float* __restrict__ bkv)
{
    __shared__ float t[32][33];
    int id = blockIdx.x;
    const int tid = threadIdx.x;
    if (id >= 7488) {   // bias-prep block
        for (int i = tid; i < 768; i += 256) {
            bqs[i] = bq[i] * 0.125f;
            bkv[i] = bk[i];
            bkv[768 + i] = bv[i];
        }
        return;
    }
    const float* src; u16* dst; int K, N, local; float sc = 1.f;
    if (id < 576)       { src = Wq; dst = WqT; K = 768; N = 768; local = id; sc = 0.125f; }
    else if (id < 1152) { src = Wk; dst = WkvT;            K = 768; N = 768; local = id - 576; }
    else if (id < 1728) { src = Wv; dst = WkvT + 768 * 768; K = 768; N = 768; local = id - 1152; }
    else if (id < 2304) { src = Wo; dst = WoT; K = 768; N = 768; local = id - 1728; }
    else if (id < 2880) { src = Wm; dst = WmT; K = 768; N = 768; local = id - 2304; }
    else if (id < 5184) { src = W1; dst = W1T; K = 768; N = 3072; local = id - 2880; }
    else                { src = W2; dst = W2T; K = 3072; N = 768; local = id - 5184; }
    const int ntiles = N >> 5;
    const int n0 = (local % ntiles) * 32, k0 = (local / ntiles) * 32;
    const int tx = tid & 31, ty = tid >> 5;
    #pragma unroll
    for (int i = 0; i < 4; i++)
        t[ty + i * 8][tx] = src[(size_t)(k0 + ty + i * 8) * N + n0 + tx];
    __syncthreads();
    #pragma unroll
    for (int i = 0; i < 4; i++)
        dst[(size_t)(n0 + ty + i * 8) * K + k0 + tx] = f2bf(t[tx][ty + i * 8] * sc);
}

// ---------------- bf16 MFMA GEMM: C = epi(A[M][K] @ WT[N][K]^T + bias) ----------------
// EPI: 0 fp32, 1 bf16, 2 gelu->bf16, 3 merge->h fp32, 4 +hres fp32
// RMAP: A row gathered through rowmap[]
// TM: 128 (4 waves 2x2, 64x64 each) or 64 (4 waves 1x4, 64x32 each); TN fixed 128.
// R15: counted-vmcnt ring pipeline (T4), K-step 32, 4 LDS buffers, 3 stages
// in flight, raw s_barrier + literal vmcnt.
// R17 FIX: R15's swizzle sigma(row)=row&3 caused 7.08M bank conflicts — a
// 64B row spans only 16 banks, and row&3 is constant-parity across a
// quarter-wave's even/odd lanes -> 4 lanes/slot (4-way). sigma=(row>>1)&3
// cycles 0..3 over 8 same-parity rows -> every (parity x chunk) slot in the
// 128B bank window hit exactly 2x = free (m136). Write chunk (s&3)^((s>>3)&3),
// read position quad^((row>>1)&3). Data contents/accum order unchanged.
template <int EPI, bool RMAP, int TM>
__global__ __launch_bounds__(256) void mfma_gemm(
    const u16* __restrict__ A, const u16* __restrict__ Bt,
    const float* __restrict__ bias, void* __restrict__ Cout,
    int N, int K, int nbn,
    const float* __restrict__ x, const unsigned* __restrict__ msk,
    const float* __restrict__ attn, const float* __restrict__ scores,
    const float* __restrict__ pWm, const float* __restrict__ hres,
    const int* __restrict__ rowmap, const int* __restrict__ invmap)
{
    constexpr int NI = (TM == 128) ? 4 : 2;
    constexpr int AL = TM / 64;            // A gl16s per stage per thread (2 or 1)
    __shared__ u16 Asm[4][TM * 32];
    __shared__ u16 Bsm[4][128 * 32];
    const int tid = threadIdx.x;
    const int wave = tid >> 6, lane = tid & 63;
    const int quad = lane >> 4, l15 = lane & 15;

    const int nwg = gridDim.x;
    const int bid = blockIdx.x;
    // bijective only when nwg%8==0 (all GEMM grids here: 768/120/1536)
    const int wid = ((nwg & 7) == 0) ? ((bid & 7) * (nwg >> 3) + (bid >> 3)) : bid;
    const int m0 = (wid / nbn) * TM, n0 = (wid % nbn) * 128;
    const int wm = (TM == 128) ? (wave >> 1) * 64 : 0;
    const int wn = (TM == 128) ? (wave & 1) * 64 : wave * 32;

    f32x4 acc[4][NI];
    #pragma unroll
    for (int i = 0; i < 4; i++)
        #pragma unroll
        for (int j = 0; j < NI; j++) acc[i][j] = 0.f;

    // slot s in [0, TM*4): row = s>>2, pos p = s&3 holds k-chunk p ^ sigma(row),
    // sigma(row) = (row>>1)&3 = (s>>3)&3  (R17 conflict-free swizzle)
    const u16* ap[AL]; const u16* bp[2];
    #pragma unroll
    for (int i = 0; i < AL; i++) {
        int s = i * 256 + tid;
        int row = s >> 2;
        int cs = (s & 3) ^ ((s >> 3) & 3);
        int arow = RMAP ? rowmap[m0 + row] : (m0 + row);
        ap[i] = A + (size_t)arow * K + cs * 8;
    }
    #pragma unroll
    for (int i = 0; i < 2; i++) {
        int s = i * 256 + tid;
        int cs = (s & 3) ^ ((s >> 3) & 3);
        bp[i] = Bt + (size_t)(n0 + (s >> 2)) * K + cs * 8;
    }

    // stage one 32-wide K-subtile into ring buffer `buf`, advance pointers
    auto stage = [&](int buf) {
        #pragma unroll
        for (int i = 0; i < AL; i++) {
            gl16(ap[i], &Asm[buf][(i * 256 + wave * 64) * 8]);
            ap[i] += 32;
        }
        #pragma unroll
        for (int i = 0; i < 2; i++) {
            gl16(bp[i], &Bsm[buf][(i * 256 + wave * 64) * 8]);
            bp[i] += 32;
        }
    };
    // MFMA over one 32-wide subtile
    auto compute = [&](int buf) {
        bf16x8 af[4], bfr[NI];
        #pragma unroll
        for (int mi = 0; mi < 4; mi++) {
            int row = wm + mi * 16 + l15;
            af[mi] = *(const bf16x8*)&Asm[buf][(row * 4 + (quad ^ ((row >> 1) & 3))) * 8];
        }
        #pragma unroll
        for (int ni = 0; ni < NI; ni++) {
            int row = wn + ni * 16 + l15;
            bfr[ni] = *(const bf16x8*)&Bsm[buf][(row * 4 + (quad ^ ((row >> 1) & 3))) * 8];
        }
        #pragma unroll
        for (int mi = 0; mi < 4; mi++)
            #pragma unroll
            for (int ni = 0; ni < NI; ni++)
                acc[mi][ni] = __builtin_amdgcn_mfma_f32_16x16x32_bf16(
                    af[mi], bfr[ni], acc[mi][ni], 0, 0, 0);
    };

    const int nt = K >> 5;          // 24 or 96 here: always >= 3
    stage(0); stage(1); stage(2);   // 3 stages in flight
    for (int t = 0; t < nt; t++) {
        // wait for stage(t) only: leave the younger stages' loads in flight
        if (t < nt - 2) {
            if constexpr (TM == 128) asm volatile("s_waitcnt vmcnt(8)" ::: "memory");
            else                     asm volatile("s_waitcnt vmcnt(6)" ::: "memory");
        } else if (t == nt - 2) {
            if constexpr (TM == 128) asm volatile("s_waitcnt vmcnt(4)" ::: "memory");
            else                     asm volatile("s_waitcnt vmcnt(3)" ::: "memory");
        } else {
            asm volatile("s_waitcnt vmcnt(0)" ::: "memory");
        }
        __builtin_amdgcn_s_barrier();
        if (t + 3 < nt) stage((t + 3) & 3);
        compute(t & 3);
    }

    #pragma unroll
    for (int mi = 0; mi < 4; mi++) {
        #pragma unroll
        for (int ni = 0; ni < NI; ni++) {
            #pragma unroll
            for (int r = 0; r < 4; r++) {
                int row = m0 + wm + mi * 16 + quad * 4 + r;
                int col = n0 + wn + ni * 16 + l15;
                float v = acc[mi][ni][r] + bias[col];
                size_t off = (size_t)row * N + col;
                if (EPI == 0) ((float*)Cout)[off] = v;
                else if (EPI == 1) ((u16*)Cout)[off] = f2bf(v);
                else if (EPI == 2) ((u16*)Cout)[off] = f2bf(gelu_tanh(v));
                else if (EPI == 3) {
                    float mix = v + scores[row] * pWm[(row >> 11) * D_ + col];
                    float sel = msk[row] ? attn[(size_t)invmap[row] * D_ + col] : mix;
                    ((float*)Cout)[off] = x[off] + sel;
                } else {
                    ((float*)Cout)[off] = v + hres[off];
                }
            }
        }
    }
}

// ---------------- V transpose: V[token][ld slice] -> VT[(b*H+h)*64+d][L] ----------------
__global__ __launch_bounds__(256) void vtrans(
    const u16* __restrict__ V, u16* __restrict__ VT, int ld)
{
    __shared__ u16 tl[64 * 72];
    const int tid = threadIdx.x;
    const int l0 = blockIdx.x * 64, h = blockIdx.y, b = blockIdx.z;
    const u16* src = V + h * 64;
    {
        int r = tid >> 3, ch = tid & 7;
        *(uint4*)&tl[r * 72 + ch * 8] =
            *(const uint4*)&src[(size_t)(b * L_ + l0 + r) * ld + ch * 8];
        int t2 = tid + 256; r = t2 >> 3; ch = t2 & 7;
        *(uint4*)&tl[r * 72 + ch * 8] =
            *(const uint4*)&src[(size_t)(b * L_ + l0 + r) * ld + ch * 8];
    }
    __syncthreads();
    int d = tid >> 2, lg = (tid & 3) * 16;
    u16* dst = VT + (size_t)((b * H_ + h) * 64 + d) * L_ + l0 + lg;
    union { u16 s[8]; uint4 v; } pk;
    #pragma unroll
    for (int j = 0; j < 8; j++) pk.s[j] = tl[(lg + j) * 72 + d];
    *(uint4*)dst = pk.v;
    #pragma unroll
    for (int j = 0; j < 8; j++) pk.s[j] = tl[(lg + 8 + j) * 72 + d];
    *(uint4*)(dst + 8) = pk.v;
}

// ---------------- compacted-Q MFMA attention, fixed-shift softmax ----------------
// R14: K/V double-buffered (2-phase): attn2 runs 240 blocks < 256 CUs ->
// 1 block/CU, zero TLP; prefetch tile t+1 under compute of t.
__global__ __launch_bounds__(256) void attn2(
    const u16* __restrict__ qcomp, const u16* __restrict__ Kg,
    const u16* __restrict__ VTg, u16* __restrict__ ctxc)
{
    __shared__ u16 Qs[64 * 64];
    __shared__ u16 Ks[2][64 * 64];
    __shared__ u16 Vs[2][64 * 64];
    __shared__ u16 Ps[4 * 16 * 72];
    const int tid = threadIdx.x, wave = tid >> 6, lane = tid & 63;
    const int quad = lane >> 4, l15 = lane & 15;
    const int qb = blockIdx.x, h = blockIdx.y, b = blockIdx.z;
    const int q0 = qb * 64;

    {
        int s0 = wave * 64 + lane;
        int r = s0 >> 3, c = (s0 & 7) ^ (r & 7);
        gl16(qcomp + (size_t)(b * KPAD + q0 + r) * D_ + h * 64 + c * 8,
             &Qs[(wave * 64) * 8]);
        int s1 = s0 + 256;
        int r1 = s1 >> 3, c1 = (s1 & 7) ^ (r1 & 7);
        gl16(qcomp + (size_t)(b * KPAD + q0 + r1) * D_ + h * 64 + c1 * 8,
             &Qs[(256 + wave * 64) * 8]);
    }
    const u16 *kp0, *kp1, *vp0, *vp1;
    {
        int s0 = wave * 64 + lane;
        int r = s0 >> 3, c = (s0 & 7) ^ (r & 7);
        kp0 = Kg + (size_t)(b * L_ + r) * 1536 + h * 64 + c * 8;
        vp0 = VTg + (size_t)((b * H_ + h) * 64 + r) * L_ + c * 8;
        int s1 = s0 + 256;
        int r1 = s1 >> 3, c1 = (s1 & 7) ^ (r1 & 7);
        kp1 = Kg + (size_t)(b * L_ + r1) * 1536 + h * 64 + c1 * 8;
        vp1 = VTg + (size_t)((b * H_ + h) * 64 + r1) * L_ + c1 * 8;
    }
    // prologue: stage K/V tile 0 into buf 0 (alongside the Q stage above)
    gl16(kp0, &Ks[0][(wave * 64) * 8]);        kp0 += (size_t)64 * 1536;
    gl16(kp1, &Ks[0][(256 + wave * 64) * 8]);  kp1 += (size_t)64 * 1536;
    gl16(vp0, &Vs[0][(wave * 64) * 8]);        vp0 += 64;
    gl16(vp1, &Vs[0][(256 + wave * 64) * 8]);  vp1 += 64;
    wait_vm0();
    __syncthreads();
    bf16x8 qf0, qf1;
    {
        int row = wave * 16 + l15;
        qf0 = *(const bf16x8*)&Qs[(row * 8 + ((quad)     ^ (row & 7))) * 8];
        qf1 = *(const bf16x8*)&Qs[(row * 8 + ((4 + quad) ^ (row & 7))) * 8];
    }
    f32x4 accO[4]; float lp[4];
    #pragma unroll
    for (int i = 0; i < 4; i++) { accO[i] = 0.f; lp[i] = 0.f; }
    u16* Psw = Ps + wave * 16 * 72;

    for (int kt = 0; kt < L_; kt += 64) {
        const int buf = (kt >> 6) & 1;
        if (kt + 64 < L_) {         // prefetch tile t+1 into the other buffer
            gl16(kp0, &Ks[buf ^ 1][(wave * 64) * 8]);        kp0 += (size_t)64 * 1536;
            gl16(kp1, &Ks[buf ^ 1][(256 + wave * 64) * 8]);  kp1 += (size_t)64 * 1536;
            gl16(vp0, &Vs[buf ^ 1][(wave * 64) * 8]);        vp0 += 64;
            gl16(vp1, &Vs[buf ^ 1][(256 + wave * 64) * 8]);  vp1 += 64;
        }

        f32x4 accS[4];
        #pragma unroll
        for (int ni = 0; ni < 4; ni++) accS[ni] = 0.f;
        #pragma unroll
        for (int kk = 0; kk < 2; kk++) {
            const int kq = kk * 4 + quad;
            #pragma unroll
            for (int ni = 0; ni < 4; ni++) {
                int row = ni * 16 + l15;
                bf16x8 kf = *(const bf16x8*)&Ks[buf][(row * 8 + (kq ^ (row & 7))) * 8];
                accS[ni] = __builtin_amdgcn_mfma_f32_16x16x32_bf16(
                    kk ? qf1 : qf0, kf, accS[ni], 0, 0, 0);
            }
        }
        #pragma unroll
        for (int ni = 0; ni < 4; ni++) {
            #pragma unroll
            for (int r = 0; r < 4; r++) {
                float p = __expf(accS[ni][r]);
                lp[r] += p;
                Psw[(quad * 4 + r) * 72 + ni * 16 + l15] = f2bf(p);
            }
        }
        #pragma unroll
        for (int kk = 0; kk < 2; kk++) {
            bf16x8 pf = *(const bf16x8*)&Psw[l15 * 72 + kk * 32 + quad * 8];
            const int kq = kk * 4 + quad;
            #pragma unroll
            for (int ni = 0; ni < 4; ni++) {
                int row = ni * 16 + l15;
                bf16x8 vf = *(const bf16x8*)&Vs[buf][(row * 8 + (kq ^ (row & 7))) * 8];
                accO[ni] = __builtin_amdgcn_mfma_f32_16x16x32_bf16(pf, vf, accO[ni], 0, 0, 0);
            }
        }
        wait_vm0();                 // prefetch landed; barrier guards buf swap
        __syncthreads();
    }

    float invl[4];
    #pragma unroll
    for (int r = 0; r < 4; r++) {
        float s = lp[r];
        s += __shfl_xor(s, 1, 64); s += __shfl_xor(s, 2, 64);
        s += __shfl_xor(s, 4, 64); s += __shfl_xor(s, 8, 64);
        invl[r] = 1.0f / s;
    }
    #pragma unroll
    for (int ni = 0; ni < 4; ni++) {
        #pragma unroll
        for (int r = 0; r < 4; r++) {
            int ql = q0 + wave * 16 + quad * 4 + r;
            if (ql < KTOP)
                ctxc[(size_t)(b * KPAD + ql) * D_ + h * 64 + ni * 16 + l15] =
                    f2bf(accO[ni][r] * invl[r]);
        }
    }
}

// ---------------- launch ----------------
extern "C" void kernel_launch(void* const* d_in, const int* in_sizes, int n_in,
                              void* d_out, int out_size, void* d_ws, size_t ws_size,
                              hipStream_t stream)
{
    const float* x   = (const float*)d_in[0];
    const float* g1  = (const float*)d_in[1];
    const float* b1  = (const float*)d_in[2];
    const float* g2  = (const float*)d_in[3];
    const float* b2  = (const float*)d_in[4];
    const float* Wr  = (const float*)d_in[5];
    const float* br  = (const float*)d_in[6];
    const float* Wq  = (const float*)d_in[7];
    const float* bq  = (const float*)d_in[8];
    const float* Wk  = (const float*)d_in[9];
    const float* bk  = (const float*)d_in[10];
    const float* Wv  = (const float*)d_in[11];
    const float* bv  = (const float*)d_in[12];
    const float* Wo  = (const float*)d_in[13];
    const float* bo  = (const float*)d_in[14];
    const float* Wm  = (const float*)d_in[15];
    const float* bm  = (const float*)d_in[16];
    const float* W1  = (const float*)d_in[17];
    const float* bf1 = (const float*)d_in[18];
    const float* W2  = (const float*)d_in[19];
    const float* bf2 = (const float*)d_in[20];
    float* out = (float*)d_out;

    char* W = (char*)d_ws;
    u16* WqT  = (u16*)(W + 0);
    u16* WkvT = (u16*)(W + 1179648);
    u16* WoT  = (u16*)(W + 3538944);
    u16* WmT  = (u16*)(W + 4718592);
    u16* W1T  = (u16*)(W + 5898240);
    u16* W2T  = (u16*)(W + 10616832);
    float* scores  = (float*)(W + 15335424);
    unsigned* mask = (unsigned*)(W + 15368192);
    float* ssum    = (float*)(W + 15400960);
    float* pWm     = (float*)(W + 15413504);
    float* bkv     = (float*)(W + 15524096);
    float* bqs     = (float*)(W + 15530240);
    int* rowmap    = (int*)(W + 15533312);
    int* invmap    = (int*)(W + 15538432);
    u16* nb    = (u16*)(W + 15728640);
    u16* Y     = (u16*)(W + 28311552);
    u16* qcomp = (u16*)(W + 53477376);
    u16* ctxc  = (u16*)(W + 55443456);
    float* attnc = (float*)(W + 57409536);
    u16* VT    = (u16*)(W + 61341696);
    float* h   = (float*)(W + 28311552);
    u16* n2b   = (u16*)(W + 15728640);
    u16* mid   = (u16*)(W + 53477376);
    // R11: parts grew to 64 chunks x B x D fp32 (786KB) — aliases the qcomp
    // region, which is dead until the Q-projection (pooled_* run before it).
    float* parts = (float*)(W + 53477376);

    wconv_all<<<7489, 256, 0, stream>>>(Wq, Wk, Wv, Wo, Wm, W1, W2,
                                        WqT, WkvT, WoT, WmT, W1T, W2T,
                                        bq, bk, bv, bqs, bkv);

    const int NT = B_ * L_;
    ln_kernel<true><<<NT, 256, 0, stream>>>(x, g1, b1, Wr, br, nb, scores);
    topk_kernel<<<B_, 1024, 0, stream>>>(scores, mask, ssum, rowmap, invmap);
    pooled_part<<<dim3(64, B_), 256, 0, stream>>>(scores, nb, parts);
    pooled_wm<<<dim3(12, B_), 256, 0, stream>>>(parts, ssum, Wm, pWm);

    // dense KV projection -> Y [8192][1536]  (64 m x 12 n = 768 blocks)
    mfma_gemm<1, false, 128><<<768, 256, 0, stream>>>(nb, WkvT, bkv, Y, 1536, 768, 12,
        nullptr, nullptr, nullptr, nullptr, nullptr, nullptr, nullptr, nullptr);
    // gathered Q projection (scaled 1/8) -> qcomp [1280][768]  (20 m x 6 n = 120)
    mfma_gemm<1, true, 64><<<120, 256, 0, stream>>>(nb, WqT, bqs, qcomp, 768, 768, 6,
        nullptr, nullptr, nullptr, nullptr, nullptr, nullptr, rowmap, nullptr);
    // V transpose -> VT
    vtrans<<<dim3(32, H_, B_), 256, 0, stream>>>(Y + 768, VT, 1536);
    // compacted attention -> ctxc
    attn2<<<dim3(KPAD / 64, H_, B_), 256, 0, stream>>>(qcomp, Y, VT, ctxc);
    // attn_out (compact) = ctxc @ Wo + bo  (20 m x 6 n = 120)
    mfma_gemm<0, false, 64><<<120, 256, 0, stream>>>(ctxc, WoT, bo, attnc, 768, 768, 6,
        nullptr, nullptr, nullptr, nullptr, nullptr, nullptr, nullptr, nullptr);
    // h = x + where(mask, attnc[inv], normed@Wm + bm + s*pWm)  (128 m x 6 n = 768)
    mfma_gemm<3, false, 64><<<768, 256, 0, stream>>>(nb, WmT, bm, h, 768, 768, 6,
        x, mask, attnc, scores, pWm, nullptr, nullptr, invmap);
    // LN2 -> n2b
    ln_kernel<false><<<NT, 256, 0, stream>>>(h, g2, b2, nullptr, nullptr, n2b, nullptr);
    // FFN1 (TM=128, 64 m x 24 n = 1536 blocks)
    mfma_gemm<2, false, 128><<<1536, 256, 0, stream>>>(n2b, W1T, bf1, mid, 3072, 768, 24,
        nullptr, nullptr, nullptr, nullptr, nullptr, nullptr, nullptr, nullptr);
    // FFN2 (128 m x 6 n = 768)
    mfma_gemm<4, false, 64><<<768, 256, 0, stream>>>(mid, W2T, bf2, out, 768, 3072, 6,
        nullptr, nullptr, nullptr, nullptr, nullptr, h, nullptr, nullptr);
}

// Round 19
// 419.504 us; speedup vs baseline: 1.1070x; 1.0981x over previous
//
#include <hip/hip_runtime.h>
#include <math.h>

#define B_ 4
#define L_ 2048
#define D_ 768
#define H_ 12
#define F_ 3072
#define KTOP 307
#define KPAD 320
#define LN_EPS 1e-5f

typedef unsigned int u32;
typedef unsigned short u16;
using bf16x8 = __attribute__((ext_vector_type(8))) short;
using f32x4  = __attribute__((ext_vector_type(4))) float;

#define AS1 __attribute__((address_space(1)))
#define AS3 __attribute__((address_space(3)))

__device__ __forceinline__ void gl16(const void* g, void* l) {
    __builtin_amdgcn_global_load_lds((const AS1 u32*)g, (AS3 u32*)l, 16, 0, 0);
}
// explicit drain of the global_load_lds queue before barriers
__device__ __forceinline__ void wait_vm0() {
    asm volatile("s_waitcnt vmcnt(0)" ::: "memory");
}
__device__ __forceinline__ u16 f2bf(float f) {
    u32 u = __float_as_uint(f);
    return (u16)((u + 0x7fff + ((u >> 16) & 1)) >> 16);
}
__device__ __forceinline__ float bf2f(u16 s) {
    return __uint_as_float(((u32)s) << 16);
}
// tanh-form GELU: ~8 VALU ops vs ~30 for erff; |err| <= ~1e-3 << bf16 quantization.
__device__ __forceinline__ float gelu_tanh(float v) {
    float u = v * v * v;
    float z = fmaf(u, 0.0713548163f, 1.59576912f * v);
    float s = __builtin_amdgcn_rcpf(1.0f + __expf(-z));
    return v * s;
}

// ---------------- block reduce (256 threads) ----------------
__device__ __forceinline__ float blk_reduce_sum(float v, float* red) {
    #pragma unroll
    for (int off = 32; off; off >>= 1) v += __shfl_xor(v, off, 64);
    __syncthreads();
    if ((threadIdx.x & 63) == 0) red[threadIdx.x >> 6] = v;
    __syncthreads();
    return red[0] + red[1] + red[2] + red[3];
}
// dual-value block reduce: one butterfly pass carries sum AND sumsq (R11:
// halves the LN reduce rounds — 2 barriers instead of 4, 6 shuffle pairs).
__device__ __forceinline__ void blk_reduce_sum2(
    float a, float b, float* red, float& oa, float& ob)
{
    #pragma unroll
    for (int off = 32; off; off >>= 1) {
        a += __shfl_xor(a, off, 64);
        b += __shfl_xor(b, off, 64);
    }
    __syncthreads();
    if ((threadIdx.x & 63) == 0) {
        int w = threadIdx.x >> 6;
        red[w] = a; red[4 + w] = b;
    }
    __syncthreads();
    oa = red[0] + red[1] + red[2] + red[3];
    ob = red[4] + red[5] + red[6] + red[7];
}

// ---------------- LN -> bf16 normed (+ optional fp32 router score) ----------------
// var = E[x^2] - mean^2 (fp32; cancellation error ~1e-7 << bf16 quantization)
template <bool SCORE>
__global__ __launch_bounds__(256) void ln_kernel(
    const float* __restrict__ x, const float* __restrict__ g,
    const float* __restrict__ be, const float* __restrict__ Wr,
    const float* __restrict__ brp, u16* __restrict__ outn,
    float* __restrict__ scores)
{
    __shared__ float red[8];
    const int t = blockIdx.x;
    const int tid = threadIdx.x;
    const float* xr = x + (size_t)t * D_;
    float v0 = xr[tid], v1 = xr[tid + 256], v2 = xr[tid + 512];
    float s1, s2;
    blk_reduce_sum2(v0 + v1 + v2,
                    fmaf(v0, v0, fmaf(v1, v1, v2 * v2)), red, s1, s2);
    float mean = s1 * (1.0f / 768.0f);
    float var  = fmaf(-mean, mean, s2 * (1.0f / 768.0f));
    float inv = 1.0f / sqrtf(fmaxf(var, 0.f) + LN_EPS);
    float n0 = (v0 - mean) * inv * g[tid] + be[tid];
    float n1 = (v1 - mean) * inv * g[tid + 256] + be[tid + 256];
    float n2 = (v2 - mean) * inv * g[tid + 512] + be[tid + 512];
    u16* orow = outn + (size_t)t * D_;
    orow[tid] = f2bf(n0); orow[tid + 256] = f2bf(n1); orow[tid + 512] = f2bf(n2);
    if (SCORE) {
        __syncthreads();
        float dot = blk_reduce_sum(n0 * Wr[tid] + n1 * Wr[tid + 256] + n2 * Wr[tid + 512], red);
        if (tid == 0) scores[t] = 1.0f / (1.0f + expf(-(dot + brp[0])));
    }
}

// ---------------- exact radix-select top-k (lowest KTOP scores) ----------------
// 1 block/batch, 1024 threads. u32 bit order == float order (scores > 0).
// Selection set identical to sorting composite keys (score_bits<<32)|index:
// all score<s*, plus lowest-index `want` among score==s*.
__global__ __launch_bounds__(1024) void topk_kernel(
    const float* __restrict__ scores, unsigned* __restrict__ mask,
    float* __restrict__ ssum, int* __restrict__ rowmap, int* __restrict__ inv)
{
    __shared__ u32 sb[L_];
    __shared__ u32 hist[256];
    __shared__ u32 wsum[16];
    __shared__ float redf[16];
    __shared__ u32 bcast[2];
    __shared__ u32 cnt_sel;
    const int b = blockIdx.x, tid = threadIdx.x;
    const int lane = tid & 63, wv = tid >> 6;

    if (tid == 0) cnt_sel = 0;
    float s0 = scores[b * L_ + tid];
    float s1 = scores[b * L_ + tid + 1024];
    sb[tid] = __float_as_uint(s0);
    sb[tid + 1024] = __float_as_uint(s1);
    float v = s0 + s1;
    #pragma unroll
    for (int o = 32; o; o >>= 1) v += __shfl_xor(v, o, 64);
    if (lane == 0) redf[wv] = v;
    __syncthreads();
    if (tid == 0) {
        float t = 0.f;
        #pragma unroll
        for (int w = 0; w < 16; w++) t += redf[w];
        ssum[b] = t;
    }

    u32 want = KTOP, prefix = 0;
    #pragma unroll
    for (int pass = 0; pass < 4; pass++) {
        const int shift = 24 - pass * 8;
        if (tid < 256) hist[tid] = 0;
        __syncthreads();
        u32 x0 = sb[tid], x1 = sb[tid + 1024];
        if (pass == 0 || (x0 >> (shift + 8)) == prefix) atomicAdd(&hist[(x0 >> shift) & 255], 1u);
        if (pass == 0 || (x1 >> (shift + 8)) == prefix) atomicAdd(&hist[(x1 >> shift) & 255], 1u);
        __syncthreads();
        u32 c = 0, inc = 0;
        if (tid < 256) {
            c = hist[tid];
            inc = c;
            #pragma unroll
            for (int o = 1; o < 64; o <<= 1) {
                u32 t = __shfl_up(inc, o, 64);
                if (lane >= o) inc += t;
            }
            if (lane == 63) wsum[wv] = inc;
        }
        __syncthreads();
        if (tid < 256) {
            u32 base = 0;
            #pragma unroll
            for (int w = 0; w < 4; w++) if (w < wv) base += wsum[w];
            u32 incl = base + inc;
            u32 excl = incl - c;
            if (excl < want && want <= incl) {
                bcast[0] = (u32)tid;
                bcast[1] = want - excl;
            }
        }
        __syncthreads();
        prefix = (prefix << 8) | bcast[0];
        want = bcast[1];
    }

    // tie-break among score==s* by lowest index: block prefix-scan of eq flags
    const u32 sstar = prefix;
    u32 a0 = sb[2 * tid], a1 = sb[2 * tid + 1];
    u32 e0 = (a0 == sstar) ? 1u : 0u, e1 = (a1 == sstar) ? 1u : 0u;
    u32 ps = e0 + e1, inc2 = ps;
    #pragma unroll
    for (int o = 1; o < 64; o <<= 1) {
        u32 t = __shfl_up(inc2, o, 64);
        if (lane >= o) inc2 += t;
    }
    __syncthreads();          // wsum reuse: ensure pass-3 readers done
    if (lane == 63) wsum[wv] = inc2;
    __syncthreads();
    u32 base = 0;
    #pragma unroll
    for (int w = 0; w < 16; w++) if (w < wv) base += wsum[w];
    u32 excl0 = base + inc2 - ps;   // eq-rank of position 2*tid
    {
        int i = 2 * tid;
        bool sel = (a0 < sstar) || (e0 && (excl0 < want));
        mask[b * L_ + i] = sel ? 1u : 0u;
        int invv = 0;
        if (sel) {
            u32 slot = atomicAdd(&cnt_sel, 1u);
            rowmap[b * KPAD + slot] = b * L_ + i;
            invv = b * KPAD + (int)slot;
        }
        inv[b * L_ + i] = invv;
    }
    {
        int i = 2 * tid + 1;
        u32 r1 = excl0 + e0;
        bool sel = (a1 < sstar) || (e1 && (r1 < want));
        mask[b * L_ + i] = sel ? 1u : 0u;
        int invv = 0;
        if (sel) {
            u32 slot = atomicAdd(&cnt_sel, 1u);
            rowmap[b * KPAD + slot] = b * L_ + i;
            invv = b * KPAD + (int)slot;
        }
        inv[b * L_ + i] = invv;
    }
    if (tid < KPAD - KTOP)
        rowmap[b * KPAD + KTOP + tid] = b * L_;   // padding rows: any valid token
}

// ---------------- pooled partials (R11: 64 L-chunks -> 256 blocks, was 32) ----------------
__global__ __launch_bounds__(256) void pooled_part(
    const float* __restrict__ scores, const u16* __restrict__ nb,
    float* __restrict__ parts)
{
    const int lc = blockIdx.x, b = blockIdx.y, tid = threadIdx.x;
    float a0 = 0.f, a1 = 0.f, a2 = 0.f;
    const int l0 = lc * 32;
    for (int l = l0; l < l0 + 32; l++) {
        float s = scores[b * L_ + l];
        const u16* row = nb + (size_t)(b * L_ + l) * D_;
        a0 += s * bf2f(row[tid]);
        a1 += s * bf2f(row[tid + 256]);
        a2 += s * bf2f(row[tid + 512]);
    }
    float* p = parts + (size_t)(lc * B_ + b) * D_;
    p[tid] = a0; p[tid + 256] = a1; p[tid + 512] = a2;
}

// ---------------- fused: pooled = (sum parts)/ssum; pWm = pooled @ Wm ----------------
// R11: 48 blocks (was 12): block = 64 n-cols x 4-way k-split + LDS reduce.
__global__ __launch_bounds__(256) void pooled_wm(
    const float* __restrict__ parts, const float* __restrict__ ssum,
    const float* __restrict__ Wm, float* __restrict__ pWm)
{
    __shared__ float pl[768];
    __shared__ float red2[4][64];
    const int b = blockIdx.y, n0 = blockIdx.x * 64, tid = threadIdx.x;
    float inv = 1.0f / (ssum[b] + 1e-6f);
    for (int d = tid; d < 768; d += 256) {
        float s = 0.f;
        #pragma unroll 8
        for (int lc = 0; lc < 64; lc++) s += parts[(size_t)(lc * B_ + b) * D_ + d];
        pl[d] = s * inv;
    }
    __syncthreads();
    const int nl = tid & 63, kq = tid >> 6;
    const int n = n0 + nl;
    float acc = 0.f;
    const int k0 = kq * 192;
    for (int k = k0; k < k0 + 192; k++)
        acc = fmaf(pl[k], Wm[(size_t)k * D_ + n], acc);
    red2[kq][nl] = acc;
    __syncthreads();
    if (kq == 0)
        pWm[b * D_ + n] = red2[0][nl] + red2[1][nl] + red2[2][nl] + red2[3][nl];
}

// ---------------- fused weight convert+transpose (7 weights + biases, 1 launch) ----------------
__global__ __launch_bounds__(256) void wconv_all(
    const float* __restrict__ Wq, const float* __restrict__ Wk,
    const float* __restrict__ Wv, const float* __restrict__ Wo,
    const float* __restrict__ Wm, const float* __restrict__ W1,
    const float* __restrict__ W2,
    u16* __restrict__ WqT, u16* __restrict__ WkvT, u16* __restrict__ WoT,
    u16* __restrict__ WmT, u16* __restrict__ W1T, u16* __restrict__ W2T,
    const float* __restrict__ bq, const float* __restrict__ bk,
    const float* __restrict__ bv, float* __restrict__ bqs,
    float* __restrict__ bkv)
{
    __shared__ float t[32][33];
    int id = blockIdx.x;
    const int tid = threadIdx.x;
    if (id >= 7488) {   // bias-prep block
        for (int i = tid; i < 768; i += 256) {
            bqs[i] = bq[i] * 0.125f;
            bkv[i] = bk[i];
            bkv[768 + i] = bv[i];
        }
        return;
    }
    const float* src; u16* dst; int K, N, local; float sc = 1.f;
    if (id < 576)       { src = Wq; dst = WqT; K = 768; N = 768; local = id; sc = 0.125f; }
    else if (id < 1152) { src = Wk; dst = WkvT;            K = 768; N = 768; local = id - 576; }
    else if (id < 1728) { src = Wv; dst = WkvT + 768 * 768; K = 768; N = 768; local = id - 1152; }
    else if (id < 2304) { src = Wo; dst = WoT; K = 768; N = 768; local = id - 1728; }
    else if (id < 2880) { src = Wm; dst = WmT; K = 768; N = 768; local = id - 2304; }
    else if (id < 5184) { src = W1; dst = W1T; K = 768; N = 3072; local = id - 2880; }
    else                { src = W2; dst = W2T; K = 3072; N = 768; local = id - 5184; }
    const int ntiles = N >> 5;
    const int n0 = (local % ntiles) * 32, k0 = (local / ntiles) * 32;
    const int tx = tid & 31, ty = tid >> 5;
    #pragma unroll
    for (int i = 0; i < 4; i++)
        t[ty + i * 8][tx] = src[(size_t)(k0 + ty + i * 8) * N + n0 + tx];
    __syncthreads();
    #pragma unroll
    for (int i = 0; i < 4; i++)
        dst[(size_t)(n0 + ty + i * 8) * K + k0 + tx] = f2bf(t[tx][ty + i * 8] * sc);
}

// ---------------- bf16 MFMA GEMM: C = epi(A[M][K] @ WT[N][K]^T + bias) ----------------
// EPI: 0 fp32, 1 bf16, 2 gelu->bf16, 3 merge->h fp32, 4 +hres fp32
// RMAP: A row gathered through rowmap[]
// TM: 128 (4 waves 2x2, 64x64 each) or 64 (4 waves 1x4, 64x32 each); TN fixed 128.
// K-loop: 2-phase double-buffered LDS (T3 minimum recipe): STAGE(t+1) issued
// before COMPUTE(t); one vmcnt(0)+barrier per tile. nt = K/64 is always even.
// Block mapping: XCD-chunked swizzle (T1, R11: -14.5us).
// R18 REVERT: counted-vmcnt ring (R15/R17, K-step 32, 4 bufs) measured WORSE
// even after fixing its bank conflicts to 0 (75.6us vs 61.3us on FFN-class,
// VALUBusy 14% vs 37%): 2x barriers x half-size phases can't cover latency.
// T4-style deep pipelining needs the full 8-phase co-design, not a graft.
// This 2-phase K=64 structure = the measured 421.5us configuration (R13).
template <int EPI, bool RMAP, int TM>
__global__ __launch_bounds__(256) void mfma_gemm(
    const u16* __restrict__ A, const u16* __restrict__ Bt,
    const float* __restrict__ bias, void* __restrict__ Cout,
    int N, int K, int nbn,
    const float* __restrict__ x, const unsigned* __restrict__ msk,
    const float* __restrict__ attn, const float* __restrict__ scores,
    const float* __restrict__ pWm, const float* __restrict__ hres,
    const int* __restrict__ rowmap, const int* __restrict__ invmap)
{
    constexpr int NI = (TM == 128) ? 4 : 2;
    constexpr int ASLOTS = TM * 8 / 256;
    __shared__ u16 Asm[2][TM * 64];
    __shared__ u16 Bsm[2][128 * 64];
    const int tid = threadIdx.x;
    const int wave = tid >> 6, lane = tid & 63;
    const int quad = lane >> 4, l15 = lane & 15;

    const int nwg = gridDim.x;
    const int bid = blockIdx.x;
    // bijective only when nwg%8==0 (all GEMM grids here: 768/120/1536)
    const int wid = ((nwg & 7) == 0) ? ((bid & 7) * (nwg >> 3) + (bid >> 3)) : bid;
    const int m0 = (wid / nbn) * TM, n0 = (wid % nbn) * 128;
    const int wm = (TM == 128) ? (wave >> 1) * 64 : 0;
    const int wn = (TM == 128) ? (wave & 1) * 64 : wave * 32;

    f32x4 acc[4][NI];
    #pragma unroll
    for (int i = 0; i < 4; i++)
        #pragma unroll
        for (int j = 0; j < NI; j++) acc[i][j] = 0.f;

    const u16* ap[ASLOTS]; const u16* bp[4];
    #pragma unroll
    for (int i = 0; i < ASLOTS; i++) {
        int s = i * 256 + tid;
        int row = s >> 3;
        int kq = (s & 7) ^ (row & 7);
        int arow = RMAP ? rowmap[m0 + row] : (m0 + row);
        ap[i] = A + (size_t)arow * K + kq * 8;
    }
    #pragma unroll
    for (int i = 0; i < 4; i++) {
        int s = i * 256 + tid;
        int row = s >> 3;
        int kq = (s & 7) ^ (row & 7);
        bp[i] = Bt + (size_t)(n0 + row) * K + kq * 8;
    }

    // stage one 64-wide K-tile into LDS buffer `buf`, advance pointers
    auto stage = [&](int buf) {
        #pragma unroll
        for (int i = 0; i < ASLOTS; i++) {
            gl16(ap[i], &Asm[buf][(i * 256 + wave * 64) * 8]);
            ap[i] += 64;
        }
        #pragma unroll
        for (int i = 0; i < 4; i++) {
            gl16(bp[i], &Bsm[buf][(i * 256 + wave * 64) * 8]);
            bp[i] += 64;
        }
    };
    // MFMA over one staged tile
    auto compute = [&](int buf) {
        #pragma unroll
        for (int kk = 0; kk < 2; kk++) {
            bf16x8 af[4], bfr[NI];
            const int kq = kk * 4 + quad;
            #pragma unroll
            for (int mi = 0; mi < 4; mi++) {
                int row = wm + mi * 16 + l15;
                af[mi] = *(const bf16x8*)&Asm[buf][(row * 8 + (kq ^ (row & 7))) * 8];
            }
            #pragma unroll
            for (int ni = 0; ni < NI; ni++) {
                int row = wn + ni * 16 + l15;
                bfr[ni] = *(const bf16x8*)&Bsm[buf][(row * 8 + (kq ^ (row & 7))) * 8];
            }
            #pragma unroll
            for (int mi = 0; mi < 4; mi++)
                #pragma unroll
                for (int ni = 0; ni < NI; ni++)
                    acc[mi][ni] = __builtin_amdgcn_mfma_f32_16x16x32_bf16(
                        af[mi], bfr[ni], acc[mi][ni], 0, 0, 0);
        }
    };

    const int nt = K >> 6;          // 12 or 48 here: always even, >= 2
    stage(0);
    wait_vm0();
    __syncthreads();
    for (int t = 0; t < nt; t += 2) {
        stage(1);                   // prefetch tile t+1 (flies under compute)
        compute(0);
        wait_vm0();
        __syncthreads();
        if (t + 2 < nt) stage(0);   // prefetch tile t+2
        compute(1);
        if (t + 2 < nt) {           // last pair: fall through to epilogue
            wait_vm0();
            __syncthreads();
        }
    }

    #pragma unroll
    for (int mi = 0; mi < 4; mi++) {
        #pragma unroll
        for (int ni = 0; ni < NI; ni++) {
            #pragma unroll
            for (int r = 0; r < 4; r++) {
                int row = m0 + wm + mi * 16 + quad * 4 + r;
                int col = n0 + wn + ni * 16 + l15;
                float v = acc[mi][ni][r] + bias[col];
                size_t off = (size_t)row * N + col;
                if (EPI == 0) ((float*)Cout)[off] = v;
                else if (EPI == 1) ((u16*)Cout)[off] = f2bf(v);
                else if (EPI == 2) ((u16*)Cout)[off] = f2bf(gelu_tanh(v));
                else if (EPI == 3) {
                    float mix = v + scores[row] * pWm[(row >> 11) * D_ + col];
                    float sel = msk[row] ? attn[(size_t)invmap[row] * D_ + col] : mix;
                    ((float*)Cout)[off] = x[off] + sel;
                } else {
                    ((float*)Cout)[off] = v + hres[off];
                }
            }
        }
    }
}

// ---------------- V transpose: V[token][ld slice] -> VT[(b*H+h)*64+d][L] ----------------
__global__ __launch_bounds__(256) void vtrans(
    const u16* __restrict__ V, u16* __restrict__ VT, int ld)
{
    __shared__ u16 tl[64 * 72];
    const int tid = threadIdx.x;
    const int l0 = blockIdx.x * 64, h = blockIdx.y, b = blockIdx.z;
    const u16* src = V + h * 64;
    {
        int r = tid >> 3, ch = tid & 7;
        *(uint4*)&tl[r * 72 + ch * 8] =
            *(const uint4*)&src[(size_t)(b * L_ + l0 + r) * ld + ch * 8];
        int t2 = tid + 256; r = t2 >> 3; ch = t2 & 7;
        *(uint4*)&tl[r * 72 + ch * 8] =
            *(const uint4*)&src[(size_t)(b * L_ + l0 + r) * ld + ch * 8];
    }
    __syncthreads();
    int d = tid >> 2, lg = (tid & 3) * 16;
    u16* dst = VT + (size_t)((b * H_ + h) * 64 + d) * L_ + l0 + lg;
    union { u16 s[8]; uint4 v; } pk;
    #pragma unroll
    for (int j = 0; j < 8; j++) pk.s[j] = tl[(lg + j) * 72 + d];
    *(uint4*)dst = pk.v;
    #pragma unroll
    for (int j = 0; j < 8; j++) pk.s[j] = tl[(lg + 8 + j) * 72 + d];
    *(uint4*)(dst + 8) = pk.v;
}

// ---------------- compacted-Q MFMA attention, fixed-shift softmax ----------------
// R14: K/V double-buffered (2-phase): attn2 runs 240 blocks < 256 CUs ->
// 1 block/CU, zero TLP; prefetch tile t+1 under compute of t.
__global__ __launch_bounds__(256) void attn2(
    const u16* __restrict__ qcomp, const u16* __restrict__ Kg,
    const u16* __restrict__ VTg, u16* __restrict__ ctxc)
{
    __shared__ u16 Qs[64 * 64];
    __shared__ u16 Ks[2][64 * 64];
    __shared__ u16 Vs[2][64 * 64];
    __shared__ u16 Ps[4 * 16 * 72];
    const int tid = threadIdx.x, wave = tid >> 6, lane = tid & 63;
    const int quad = lane >> 4, l15 = lane & 15;
    const int qb = blockIdx.x, h = blockIdx.y, b = blockIdx.z;
    const int q0 = qb * 64;

    {
        int s0 = wave * 64 + lane;
        int r = s0 >> 3, c = (s0 & 7) ^ (r & 7);
        gl16(qcomp + (size_t)(b * KPAD + q0 + r) * D_ + h * 64 + c * 8,
             &Qs[(wave * 64) * 8]);
        int s1 = s0 + 256;
        int r1 = s1 >> 3, c1 = (s1 & 7) ^ (r1 & 7);
        gl16(qcomp + (size_t)(b * KPAD + q0 + r1) * D_ + h * 64 + c1 * 8,
             &Qs[(256 + wave * 64) * 8]);
    }
    const u16 *kp0, *kp1, *vp0, *vp1;
    {
        int s0 = wave * 64 + lane;
        int r = s0 >> 3, c = (s0 & 7) ^ (r & 7);
        kp0 = Kg + (size_t)(b * L_ + r) * 1536 + h * 64 + c * 8;
        vp0 = VTg + (size_t)((b * H_ + h) * 64 + r) * L_ + c * 8;
        int s1 = s0 + 256;
        int r1 = s1 >> 3, c1 = (s1 & 7) ^ (r1 & 7);
        kp1 = Kg + (size_t)(b * L_ + r1) * 1536 + h * 64 + c1 * 8;
        vp1 = VTg + (size_t)((b * H_ + h) * 64 + r1) * L_ + c1 * 8;
    }
    // prologue: stage K/V tile 0 into buf 0 (alongside the Q stage above)
    gl16(kp0, &Ks[0][(wave * 64) * 8]);        kp0 += (size_t)64 * 1536;
    gl16(kp1, &Ks[0][(256 + wave * 64) * 8]);  kp1 += (size_t)64 * 1536;
    gl16(vp0, &Vs[0][(wave * 64) * 8]);        vp0 += 64;
    gl16(vp1, &Vs[0][(256 + wave * 64) * 8]);  vp1 += 64;
    wait_vm0();
    __syncthreads();
    bf16x8 qf0, qf1;
    {
        int row = wave * 16 + l15;
        qf0 = *(const bf16x8*)&Qs[(row * 8 + ((quad)     ^ (row & 7))) * 8];
        qf1 = *(const bf16x8*)&Qs[(row * 8 + ((4 + quad) ^ (row & 7))) * 8];
    }
    f32x4 accO[4]; float lp[4];
    #pragma unroll
    for (int i = 0; i < 4; i++) { accO[i] = 0.f; lp[i] = 0.f; }
    u16* Psw = Ps + wave * 16 * 72;

    for (int kt = 0; kt < L_; kt += 64) {
        const int buf = (kt >> 6) & 1;
        if (kt + 64 < L_) {         // prefetch tile t+1 into the other buffer
            gl16(kp0, &Ks[buf ^ 1][(wave * 64) * 8]);        kp0 += (size_t)64 * 1536;
            gl16(kp1, &Ks[buf ^ 1][(256 + wave * 64) * 8]);  kp1 += (size_t)64 * 1536;
            gl16(vp0, &Vs[buf ^ 1][(wave * 64) * 8]);        vp0 += 64;
            gl16(vp1, &Vs[buf ^ 1][(256 + wave * 64) * 8]);  vp1 += 64;
        }

        f32x4 accS[4];
        #pragma unroll
        for (int ni = 0; ni < 4; ni++) accS[ni] = 0.f;
        #pragma unroll
        for (int kk = 0; kk < 2; kk++) {
            const int kq = kk * 4 + quad;
            #pragma unroll
            for (int ni = 0; ni < 4; ni++) {
                int row = ni * 16 + l15;
                bf16x8 kf = *(const bf16x8*)&Ks[buf][(row * 8 + (kq ^ (row & 7))) * 8];
                accS[ni] = __builtin_amdgcn_mfma_f32_16x16x32_bf16(
                    kk ? qf1 : qf0, kf, accS[ni], 0, 0, 0);
            }
        }
        #pragma unroll
        for (int ni = 0; ni < 4; ni++) {
            #pragma unroll
            for (int r = 0; r < 4; r++) {
                float p = __expf(accS[ni][r]);
                lp[r] += p;
                Psw[(quad * 4 + r) * 72 + ni * 16 + l15] = f2bf(p);
            }
        }
        #pragma unroll
        for (int kk = 0; kk < 2; kk++) {
            bf16x8 pf = *(const bf16x8*)&Psw[l15 * 72 + kk * 32 + quad * 8];
            const int kq = kk * 4 + quad;
            #pragma unroll
            for (int ni = 0; ni < 4; ni++) {
                int row = ni * 16 + l15;
                bf16x8 vf = *(const bf16x8*)&Vs[buf][(row * 8 + (kq ^ (row & 7))) * 8];
                accO[ni] = __builtin_amdgcn_mfma_f32_16x16x32_bf16(pf, vf, accO[ni], 0, 0, 0);
            }
        }
        wait_vm0();                 // prefetch landed; barrier guards buf swap
        __syncthreads();
    }

    float invl[4];
    #pragma unroll
    for (int r = 0; r < 4; r++) {
        float s = lp[r];
        s += __shfl_xor(s, 1, 64); s += __shfl_xor(s, 2, 64);
        s += __shfl_xor(s, 4, 64); s += __shfl_xor(s, 8, 64);
        invl[r] = 1.0f / s;
    }
    #pragma unroll
    for (int ni = 0; ni < 4; ni++) {
        #pragma unroll
        for (int r = 0; r < 4; r++) {
            int ql = q0 + wave * 16 + quad * 4 + r;
            if (ql < KTOP)
                ctxc[(size_t)(b * KPAD + ql) * D_ + h * 64 + ni * 16 + l15] =
                    f2bf(accO[ni][r] * invl[r]);
        }
    }
}

// ---------------- launch ----------------
extern "C" void kernel_launch(void* const* d_in, const int* in_sizes, int n_in,
                              void* d_out, int out_size, void* d_ws, size_t ws_size,
                              hipStream_t stream)
{
    const float* x   = (const float*)d_in[0];
    const float* g1  = (const float*)d_in[1];
    const float* b1  = (const float*)d_in[2];
    const float* g2  = (const float*)d_in[3];
    const float* b2  = (const float*)d_in[4];
    const float* Wr  = (const float*)d_in[5];
    const float* br  = (const float*)d_in[6];
    const float* Wq  = (const float*)d_in[7];
    const float* bq  = (const float*)d_in[8];
    const float* Wk  = (const float*)d_in[9];
    const float* bk  = (const float*)d_in[10];
    const float* Wv  = (const float*)d_in[11];
    const float* bv  = (const float*)d_in[12];
    const float* Wo  = (const float*)d_in[13];
    const float* bo  = (const float*)d_in[14];
    const float* Wm  = (const float*)d_in[15];
    const float* bm  = (const float*)d_in[16];
    const float* W1  = (const float*)d_in[17];
    const float* bf1 = (const float*)d_in[18];
    const float* W2  = (const float*)d_in[19];
    const float* bf2 = (const float*)d_in[20];
    float* out = (float*)d_out;

    char* W = (char*)d_ws;
    u16* WqT  = (u16*)(W + 0);
    u16* WkvT = (u16*)(W + 1179648);
    u16* WoT  = (u16*)(W + 3538944);
    u16* WmT  = (u16*)(W + 4718592);
    u16* W1T  = (u16*)(W + 5898240);
    u16* W2T  = (u16*)(W + 10616832);
    float* scores  = (float*)(W + 15335424);
    unsigned* mask = (unsigned*)(W + 15368192);
    float* ssum    = (float*)(W + 15400960);
    float* pWm     = (float*)(W + 15413504);
    float* bkv     = (float*)(W + 15524096);
    float* bqs     = (float*)(W + 15530240);
    int* rowmap    = (int*)(W + 15533312);
    int* invmap    = (int*)(W + 15538432);
    u16* nb    = (u16*)(W + 15728640);
    u16* Y     = (u16*)(W + 28311552);
    u16* qcomp = (u16*)(W + 53477376);
    u16* ctxc  = (u16*)(W + 55443456);
    float* attnc = (float*)(W + 57409536);
    u16* VT    = (u16*)(W + 61341696);
    float* h   = (float*)(W + 28311552);
    u16* n2b   = (u16*)(W + 15728640);
    u16* mid   = (u16*)(W + 53477376);
    // R11: parts grew to 64 chunks x B x D fp32 (786KB) — aliases the qcomp
    // region, which is dead until the Q-projection (pooled_* run before it).
    float* parts = (float*)(W + 53477376);

    wconv_all<<<7489, 256, 0, stream>>>(Wq, Wk, Wv, Wo, Wm, W1, W2,
                                        WqT, WkvT, WoT, WmT, W1T, W2T,
                                        bq, bk, bv, bqs, bkv);

    const int NT = B_ * L_;
    ln_kernel<true><<<NT, 256, 0, stream>>>(x, g1, b1, Wr, br, nb, scores);
    topk_kernel<<<B_, 1024, 0, stream>>>(scores, mask, ssum, rowmap, invmap);
    pooled_part<<<dim3(64, B_), 256, 0, stream>>>(scores, nb, parts);
    pooled_wm<<<dim3(12, B_), 256, 0, stream>>>(parts, ssum, Wm, pWm);

    // dense KV projection -> Y [8192][1536]  (64 m x 12 n = 768 blocks)
    mfma_gemm<1, false, 128><<<768, 256, 0, stream>>>(nb, WkvT, bkv, Y, 1536, 768, 12,
        nullptr, nullptr, nullptr, nullptr, nullptr, nullptr, nullptr, nullptr);
    // gathered Q projection (scaled 1/8) -> qcomp [1280][768]  (20 m x 6 n = 120)
    mfma_gemm<1, true, 64><<<120, 256, 0, stream>>>(nb, WqT, bqs, qcomp, 768, 768, 6,
        nullptr, nullptr, nullptr, nullptr, nullptr, nullptr, rowmap, nullptr);
    // V transpose -> VT
    vtrans<<<dim3(32, H_, B_), 256, 0, stream>>>(Y + 768, VT, 1536);
    // compacted attention -> ctxc
    attn2<<<dim3(KPAD / 64, H_, B_), 256, 0, stream>>>(qcomp, Y, VT, ctxc);
    // attn_out (compact) = ctxc @ Wo + bo  (20 m x 6 n = 120)
    mfma_gemm<0, false, 64><<<120, 256, 0, stream>>>(ctxc, WoT, bo, attnc, 768, 768, 6,
        nullptr, nullptr, nullptr, nullptr, nullptr, nullptr, nullptr, nullptr);
    // h = x + where(mask, attnc[inv], normed@Wm + bm + s*pWm)  (128 m x 6 n = 768)
    mfma_gemm<3, false, 64><<<768, 256, 0, stream>>>(nb, WmT, bm, h, 768, 768, 6,
        x, mask, attnc, scores, pWm, nullptr, nullptr, invmap);
    // LN2 -> n2b
    ln_kernel<false><<<NT, 256, 0, stream>>>(h, g2, b2, nullptr, nullptr, n2b, nullptr);
    // FFN1 (TM=128, 64 m x 24 n = 1536 blocks)
    mfma_gemm<2, false, 128><<<1536, 256, 0, stream>>>(n2b, W1T, bf1, mid, 3072, 768, 24,
        nullptr, nullptr, nullptr, nullptr, nullptr, nullptr, nullptr, nullptr);
    // FFN2 (128 m x 6 n = 768)
    mfma_gemm<4, false, 64><<<768, 256, 0, stream>>>(mid, W2T, bf2, out, 768, 3072, 6,
        nullptr, nullptr, nullptr, nullptr, nullptr, h, nullptr, nullptr);
}

// Round 20
// 419.247 us; speedup vs baseline: 1.1077x; 1.0006x over previous
//
#include <hip/hip_runtime.h>
#include <math.h>

#define B_ 4
#define L_ 2048
#define D_ 768
#define H_ 12
#define F_ 3072
#define KTOP 307
#define KPAD 320
#define LN_EPS 1e-5f

typedef unsigned int u32;
typedef unsigned short u16;
using bf16x8 = __attribute__((ext_vector_type(8))) short;
using f32x4  = __attribute__((ext_vector_type(4))) float;

#define AS1 __attribute__((address_space(1)))
#define AS3 __attribute__((address_space(3)))

__device__ __forceinline__ void gl16(const void* g, void* l) {
    __builtin_amdgcn_global_load_lds((const AS1 u32*)g, (AS3 u32*)l, 16, 0, 0);
}
// explicit drain of the global_load_lds queue before barriers
__device__ __forceinline__ void wait_vm0() {
    asm volatile("s_waitcnt vmcnt(0)" ::: "memory");
}
__device__ __forceinline__ u16 f2bf(float f) {
    u32 u = __float_as_uint(f);
    return (u16)((u + 0x7fff + ((u >> 16) & 1)) >> 16);
}
__device__ __forceinline__ float bf2f(u16 s) {
    return __uint_as_float(((u32)s) << 16);
}
// tanh-form GELU: ~8 VALU ops vs ~30 for erff; |err| <= ~1e-3 << bf16 quantization.
__device__ __forceinline__ float gelu_tanh(float v) {
    float u = v * v * v;
    float z = fmaf(u, 0.0713548163f, 1.59576912f * v);
    float s = __builtin_amdgcn_rcpf(1.0f + __expf(-z));
    return v * s;
}

// ---------------- block reduce (256 threads) ----------------
__device__ __forceinline__ float blk_reduce_sum(float v, float* red) {
    #pragma unroll
    for (int off = 32; off; off >>= 1) v += __shfl_xor(v, off, 64);
    __syncthreads();
    if ((threadIdx.x & 63) == 0) red[threadIdx.x >> 6] = v;
    __syncthreads();
    return red[0] + red[1] + red[2] + red[3];
}
// dual-value block reduce: one butterfly pass carries sum AND sumsq (R11:
// halves the LN reduce rounds — 2 barriers instead of 4, 6 shuffle pairs).
__device__ __forceinline__ void blk_reduce_sum2(
    float a, float b, float* red, float& oa, float& ob)
{
    #pragma unroll
    for (int off = 32; off; off >>= 1) {
        a += __shfl_xor(a, off, 64);
        b += __shfl_xor(b, off, 64);
    }
    __syncthreads();
    if ((threadIdx.x & 63) == 0) {
        int w = threadIdx.x >> 6;
        red[w] = a; red[4 + w] = b;
    }
    __syncthreads();
    oa = red[0] + red[1] + red[2] + red[3];
    ob = red[4] + red[5] + red[6] + red[7];
}

// ---------------- LN -> bf16 normed (+ optional fp32 router score) ----------------
// var = E[x^2] - mean^2 (fp32; cancellation error ~1e-7 << bf16 quantization)
template <bool SCORE>
__global__ __launch_bounds__(256) void ln_kernel(
    const float* __restrict__ x, const float* __restrict__ g,
    const float* __restrict__ be, const float* __restrict__ Wr,
    const float* __restrict__ brp, u16* __restrict__ outn,
    float* __restrict__ scores)
{
    __shared__ float red[8];
    const int t = blockIdx.x;
    const int tid = threadIdx.x;
    const float* xr = x + (size_t)t * D_;
    float v0 = xr[tid], v1 = xr[tid + 256], v2 = xr[tid + 512];
    float s1, s2;
    blk_reduce_sum2(v0 + v1 + v2,
                    fmaf(v0, v0, fmaf(v1, v1, v2 * v2)), red, s1, s2);
    float mean = s1 * (1.0f / 768.0f);
    float var  = fmaf(-mean, mean, s2 * (1.0f / 768.0f));
    float inv = 1.0f / sqrtf(fmaxf(var, 0.f) + LN_EPS);
    float n0 = (v0 - mean) * inv * g[tid] + be[tid];
    float n1 = (v1 - mean) * inv * g[tid + 256] + be[tid + 256];
    float n2 = (v2 - mean) * inv * g[tid + 512] + be[tid + 512];
    u16* orow = outn + (size_t)t * D_;
    orow[tid] = f2bf(n0); orow[tid + 256] = f2bf(n1); orow[tid + 512] = f2bf(n2);
    if (SCORE) {
        __syncthreads();
        float dot = blk_reduce_sum(n0 * Wr[tid] + n1 * Wr[tid + 256] + n2 * Wr[tid + 512], red);
        if (tid == 0) scores[t] = 1.0f / (1.0f + expf(-(dot + brp[0])));
    }
}

// ---------------- exact radix-select top-k (lowest KTOP scores) ----------------
// 1 block/batch, 1024 threads. u32 bit order == float order (scores > 0).
// Selection set identical to sorting composite keys (score_bits<<32)|index:
// all score<s*, plus lowest-index `want` among score==s*.
__global__ __launch_bounds__(1024) void topk_kernel(
    const float* __restrict__ scores, unsigned* __restrict__ mask,
    float* __restrict__ ssum, int* __restrict__ rowmap, int* __restrict__ inv)
{
    __shared__ u32 sb[L_];
    __shared__ u32 hist[256];
    __shared__ u32 wsum[16];
    __shared__ float redf[16];
    __shared__ u32 bcast[2];
    __shared__ u32 cnt_sel;
    const int b = blockIdx.x, tid = threadIdx.x;
    const int lane = tid & 63, wv = tid >> 6;

    if (tid == 0) cnt_sel = 0;
    float s0 = scores[b * L_ + tid];
    float s1 = scores[b * L_ + tid + 1024];
    sb[tid] = __float_as_uint(s0);
    sb[tid + 1024] = __float_as_uint(s1);
    float v = s0 + s1;
    #pragma unroll
    for (int o = 32; o; o >>= 1) v += __shfl_xor(v, o, 64);
    if (lane == 0) redf[wv] = v;
    __syncthreads();
    if (tid == 0) {
        float t = 0.f;
        #pragma unroll
        for (int w = 0; w < 16; w++) t += redf[w];
        ssum[b] = t;
    }

    u32 want = KTOP, prefix = 0;
    #pragma unroll
    for (int pass = 0; pass < 4; pass++) {
        const int shift = 24 - pass * 8;
        if (tid < 256) hist[tid] = 0;
        __syncthreads();
        u32 x0 = sb[tid], x1 = sb[tid + 1024];
        if (pass == 0 || (x0 >> (shift + 8)) == prefix) atomicAdd(&hist[(x0 >> shift) & 255], 1u);
        if (pass == 0 || (x1 >> (shift + 8)) == prefix) atomicAdd(&hist[(x1 >> shift) & 255], 1u);
        __syncthreads();
        u32 c = 0, inc = 0;
        if (tid < 256) {
            c = hist[tid];
            inc = c;
            #pragma unroll
            for (int o = 1; o < 64; o <<= 1) {
                u32 t = __shfl_up(inc, o, 64);
                if (lane >= o) inc += t;
            }
            if (lane == 63) wsum[wv] = inc;
        }
        __syncthreads();
        if (tid < 256) {
            u32 base = 0;
            #pragma unroll
            for (int w = 0; w < 4; w++) if (w < wv) base += wsum[w];
            u32 incl = base + inc;
            u32 excl = incl - c;
            if (excl < want && want <= incl) {
                bcast[0] = (u32)tid;
                bcast[1] = want - excl;
            }
        }
        __syncthreads();
        prefix = (prefix << 8) | bcast[0];
        want = bcast[1];
    }

    // tie-break among score==s* by lowest index: block prefix-scan of eq flags
    const u32 sstar = prefix;
    u32 a0 = sb[2 * tid], a1 = sb[2 * tid + 1];
    u32 e0 = (a0 == sstar) ? 1u : 0u, e1 = (a1 == sstar) ? 1u : 0u;
    u32 ps = e0 + e1, inc2 = ps;
    #pragma unroll
    for (int o = 1; o < 64; o <<= 1) {
        u32 t = __shfl_up(inc2, o, 64);
        if (lane >= o) inc2 += t;
    }
    __syncthreads();          // wsum reuse: ensure pass-3 readers done
    if (lane == 63) wsum[wv] = inc2;
    __syncthreads();
    u32 base = 0;
    #pragma unroll
    for (int w = 0; w < 16; w++) if (w < wv) base += wsum[w];
    u32 excl0 = base + inc2 - ps;   // eq-rank of position 2*tid
    {
        int i = 2 * tid;
        bool sel = (a0 < sstar) || (e0 && (excl0 < want));
        mask[b * L_ + i] = sel ? 1u : 0u;
        int invv = 0;
        if (sel) {
            u32 slot = atomicAdd(&cnt_sel, 1u);
            rowmap[b * KPAD + slot] = b * L_ + i;
            invv = b * KPAD + (int)slot;
        }
        inv[b * L_ + i] = invv;
    }
    {
        int i = 2 * tid + 1;
        u32 r1 = excl0 + e0;
        bool sel = (a1 < sstar) || (e1 && (r1 < want));
        mask[b * L_ + i] = sel ? 1u : 0u;
        int invv = 0;
        if (sel) {
            u32 slot = atomicAdd(&cnt_sel, 1u);
            rowmap[b * KPAD + slot] = b * L_ + i;
            invv = b * KPAD + (int)slot;
        }
        inv[b * L_ + i] = invv;
    }
    if (tid < KPAD - KTOP)
        rowmap[b * KPAD + KTOP + tid] = b * L_;   // padding rows: any valid token
}

// ---------------- pooled partials (R11: 64 L-chunks -> 256 blocks, was 32) ----------------
__global__ __launch_bounds__(256) void pooled_part(
    const float* __restrict__ scores, const u16* __restrict__ nb,
    float* __restrict__ parts)
{
    const int lc = blockIdx.x, b = blockIdx.y, tid = threadIdx.x;
    float a0 = 0.f, a1 = 0.f, a2 = 0.f;
    const int l0 = lc * 32;
    for (int l = l0; l < l0 + 32; l++) {
        float s = scores[b * L_ + l];
        const u16* row = nb + (size_t)(b * L_ + l) * D_;
        a0 += s * bf2f(row[tid]);
        a1 += s * bf2f(row[tid + 256]);
        a2 += s * bf2f(row[tid + 512]);
    }
    float* p = parts + (size_t)(lc * B_ + b) * D_;
    p[tid] = a0; p[tid + 256] = a1; p[tid + 512] = a2;
}

// ---------------- fused: pooled = (sum parts)/ssum; pWm = pooled @ Wm ----------------
// R11: 48 blocks (was 12): block = 64 n-cols x 4-way k-split + LDS reduce.
__global__ __launch_bounds__(256) void pooled_wm(
    const float* __restrict__ parts, const float* __restrict__ ssum,
    const float* __restrict__ Wm, float* __restrict__ pWm)
{
    __shared__ float pl[768];
    __shared__ float red2[4][64];
    const int b = blockIdx.y, n0 = blockIdx.x * 64, tid = threadIdx.x;
    float inv = 1.0f / (ssum[b] + 1e-6f);
    for (int d = tid; d < 768; d += 256) {
        float s = 0.f;
        #pragma unroll 8
        for (int lc = 0; lc < 64; lc++) s += parts[(size_t)(lc * B_ + b) * D_ + d];
        pl[d] = s * inv;
    }
    __syncthreads();
    const int nl = tid & 63, kq = tid >> 6;
    const int n = n0 + nl;
    float acc = 0.f;
    const int k0 = kq * 192;
    for (int k = k0; k < k0 + 192; k++)
        acc = fmaf(pl[k], Wm[(size_t)k * D_ + n], acc);
    red2[kq][nl] = acc;
    __syncthreads();
    if (kq == 0)
        pWm[b * D_ + n] = red2[0][nl] + red2[1][nl] + red2[2][nl] + red2[3][nl];
}

// ---------------- fused weight convert+transpose (7 weights + biases, 1 launch) ----------------
__global__ __launch_bounds__(256) void wconv_all(
    const float* __restrict__ Wq, const float* __restrict__ Wk,
    const float* __restrict__ Wv, const float* __restrict__ Wo,
    const float* __restrict__ Wm, const float* __restrict__ W1,
    const float* __restrict__ W2,
    u16* __restrict__ WqT, u16* __restrict__ WkvT, u16* __restrict__ WoT,
    u16* __restrict__ WmT, u16* __restrict__ W1T, u16* __restrict__ W2T,
    const float* __restrict__ bq, const float* __restrict__ bk,
    const float* __restrict__ bv, float* __restrict__ bqs,
    float* __restrict__ bkv)
{
    __shared__ float t[32][33];
    int id = blockIdx.x;
    const int tid = threadIdx.x;
    if (id >= 7488) {   // bias-prep block
        for (int i = tid; i < 768; i += 256) {
            bqs[i] = bq[i] * 0.125f;
            bkv[i] = bk[i];
            bkv[768 + i] = bv[i];
        }
        return;
    }
    const float* src; u16* dst; int K, N, local; float sc = 1.f;
    if (id < 576)       { src = Wq; dst = WqT; K = 768; N = 768; local = id; sc = 0.125f; }
    else if (id < 1152) { src = Wk; dst = WkvT;            K = 768; N = 768; local = id - 576; }
    else if (id < 1728) { src = Wv; dst = WkvT + 768 * 768; K = 768; N = 768; local = id - 1152; }
    else if (id < 2304) { src = Wo; dst = WoT; K = 768; N = 768; local = id - 1728; }
    else if (id < 2880) { src = Wm; dst = WmT; K = 768; N = 768; local = id - 2304; }
    else if (id < 5184) { src = W1; dst = W1T; K = 768; N = 3072; local = id - 2880; }
    else                { src = W2; dst = W2T; K = 3072; N = 768; local = id - 5184; }
    const int ntiles = N >> 5;
    const int n0 = (local % ntiles) * 32, k0 = (local / ntiles) * 32;
    const int tx = tid & 31, ty = tid >> 5;
    #pragma unroll
    for (int i = 0; i < 4; i++)
        t[ty + i * 8][tx] = src[(size_t)(k0 + ty + i * 8) * N + n0 + tx];
    __syncthreads();
    #pragma unroll
    for (int i = 0; i < 4; i++)
        dst[(size_t)(n0 + ty + i * 8) * K + k0 + tx] = f2bf(t[tx][ty + i * 8] * sc);
}

// ---------------- bf16 MFMA GEMM: C = epi(A[M][K] @ WT[N][K]^T + bias) ----------------
// EPI: 0 fp32, 1 bf16, 2 gelu->bf16, 3 merge->h fp32, 4 +hres fp32
// RMAP: A row gathered through rowmap[]
// TM: 128 (4 waves 2x2, 64x64 each) or 64 (4 waves 1x4, 64x32 each); TN fixed 128.
// K-loop: 2-phase double-buffered LDS (T3 minimum recipe): STAGE(t+1) issued
// before COMPUTE(t); one vmcnt(0)+barrier per tile. nt = K/64 is always even.
// Block mapping: XCD-chunked swizzle (T1, R11: -14.5us).
// SESSION PLATEAU NOTE (R19): this 2-phase structure = 419.5us total,
// MfmaUtil ~25% on the GEMM cluster. Refuted alternatives (measured):
// TM=64 occupancy (R14, flat MfmaUtil), counted-vmcnt ring K=32 x 4buf
// (R17 bank conflicts; R18 conflicts=0 but 2x barriers x half phases =
// 24% slower). Breaking ~25% requires the full 8-phase co-design.
template <int EPI, bool RMAP, int TM>
__global__ __launch_bounds__(256) void mfma_gemm(
    const u16* __restrict__ A, const u16* __restrict__ Bt,
    const float* __restrict__ bias, void* __restrict__ Cout,
    int N, int K, int nbn,
    const float* __restrict__ x, const unsigned* __restrict__ msk,
    const float* __restrict__ attn, const float* __restrict__ scores,
    const float* __restrict__ pWm, const float* __restrict__ hres,
    const int* __restrict__ rowmap, const int* __restrict__ invmap)
{
    constexpr int NI = (TM == 128) ? 4 : 2;
    constexpr int ASLOTS = TM * 8 / 256;
    __shared__ u16 Asm[2][TM * 64];
    __shared__ u16 Bsm[2][128 * 64];
    const int tid = threadIdx.x;
    const int wave = tid >> 6, lane = tid & 63;
    const int quad = lane >> 4, l15 = lane & 15;

    const int nwg = gridDim.x;
    const int bid = blockIdx.x;
    // bijective only when nwg%8==0 (all GEMM grids here: 768/120/1536)
    const int wid = ((nwg & 7) == 0) ? ((bid & 7) * (nwg >> 3) + (bid >> 3)) : bid;
    const int m0 = (wid / nbn) * TM, n0 = (wid % nbn) * 128;
    const int wm = (TM == 128) ? (wave >> 1) * 64 : 0;
    const int wn = (TM == 128) ? (wave & 1) * 64 : wave * 32;

    f32x4 acc[4][NI];
    #pragma unroll
    for (int i = 0; i < 4; i++)
        #pragma unroll
        for (int j = 0; j < NI; j++) acc[i][j] = 0.f;

    const u16* ap[ASLOTS]; const u16* bp[4];
    #pragma unroll
    for (int i = 0; i < ASLOTS; i++) {
        int s = i * 256 + tid;
        int row = s >> 3;
        int kq = (s & 7) ^ (row & 7);
        int arow = RMAP ? rowmap[m0 + row] : (m0 + row);
        ap[i] = A + (size_t)arow * K + kq * 8;
    }
    #pragma unroll
    for (int i = 0; i < 4; i++) {
        int s = i * 256 + tid;
        int row = s >> 3;
        int kq = (s & 7) ^ (row & 7);
        bp[i] = Bt + (size_t)(n0 + row) * K + kq * 8;
    }

    // stage one 64-wide K-tile into LDS buffer `buf`, advance pointers
    auto stage = [&](int buf) {
        #pragma unroll
        for (int i = 0; i < ASLOTS; i++) {
            gl16(ap[i], &Asm[buf][(i * 256 + wave * 64) * 8]);
            ap[i] += 64;
        }
        #pragma unroll
        for (int i = 0; i < 4; i++) {
            gl16(bp[i], &Bsm[buf][(i * 256 + wave * 64) * 8]);
            bp[i] += 64;
        }
    };
    // MFMA over one staged tile
    auto compute = [&](int buf) {
        #pragma unroll
        for (int kk = 0; kk < 2; kk++) {
            bf16x8 af[4], bfr[NI];
            const int kq = kk * 4 + quad;
            #pragma unroll
            for (int mi = 0; mi < 4; mi++) {
                int row = wm + mi * 16 + l15;
                af[mi] = *(const bf16x8*)&Asm[buf][(row * 8 + (kq ^ (row & 7))) * 8];
            }
            #pragma unroll
            for (int ni = 0; ni < NI; ni++) {
                int row = wn + ni * 16 + l15;
                bfr[ni] = *(const bf16x8*)&Bsm[buf][(row * 8 + (kq ^ (row & 7))) * 8];
            }
            #pragma unroll
            for (int mi = 0; mi < 4; mi++)
                #pragma unroll
                for (int ni = 0; ni < NI; ni++)
                    acc[mi][ni] = __builtin_amdgcn_mfma_f32_16x16x32_bf16(
                        af[mi], bfr[ni], acc[mi][ni], 0, 0, 0);
        }
    };

    const int nt = K >> 6;          // 12 or 48 here: always even, >= 2
    stage(0);
    wait_vm0();
    __syncthreads();
    for (int t = 0; t < nt; t += 2) {
        stage(1);                   // prefetch tile t+1 (flies under compute)
        compute(0);
        wait_vm0();
        __syncthreads();
        if (t + 2 < nt) stage(0);   // prefetch tile t+2
        compute(1);
        if (t + 2 < nt) {           // last pair: fall through to epilogue
            wait_vm0();
            __syncthreads();
        }
    }

    #pragma unroll
    for (int mi = 0; mi < 4; mi++) {
        #pragma unroll
        for (int ni = 0; ni < NI; ni++) {
            #pragma unroll
            for (int r = 0; r < 4; r++) {
                int row = m0 + wm + mi * 16 + quad * 4 + r;
                int col = n0 + wn + ni * 16 + l15;
                float v = acc[mi][ni][r] + bias[col];
                size_t off = (size_t)row * N + col;
                if (EPI == 0) ((float*)Cout)[off] = v;
                else if (EPI == 1) ((u16*)Cout)[off] = f2bf(v);
                else if (EPI == 2) ((u16*)Cout)[off] = f2bf(gelu_tanh(v));
                else if (EPI == 3) {
                    float mix = v + scores[row] * pWm[(row >> 11) * D_ + col];
                    float sel = msk[row] ? attn[(size_t)invmap[row] * D_ + col] : mix;
                    ((float*)Cout)[off] = x[off] + sel;
                } else {
                    ((float*)Cout)[off] = v + hres[off];
                }
            }
        }
    }
}

// ---------------- V transpose: V[token][ld slice] -> VT[(b*H+h)*64+d][L] ----------------
__global__ __launch_bounds__(256) void vtrans(
    const u16* __restrict__ V, u16* __restrict__ VT, int ld)
{
    __shared__ u16 tl[64 * 72];
    const int tid = threadIdx.x;
    const int l0 = blockIdx.x * 64, h = blockIdx.y, b = blockIdx.z;
    const u16* src = V + h * 64;
    {
        int r = tid >> 3, ch = tid & 7;
        *(uint4*)&tl[r * 72 + ch * 8] =
            *(const uint4*)&src[(size_t)(b * L_ + l0 + r) * ld + ch * 8];
        int t2 = tid + 256; r = t2 >> 3; ch = t2 & 7;
        *(uint4*)&tl[r * 72 + ch * 8] =
            *(const uint4*)&src[(size_t)(b * L_ + l0 + r) * ld + ch * 8];
    }
    __syncthreads();
    int d = tid >> 2, lg = (tid & 3) * 16;
    u16* dst = VT + (size_t)((b * H_ + h) * 64 + d) * L_ + l0 + lg;
    union { u16 s[8]; uint4 v; } pk;
    #pragma unroll
    for (int j = 0; j < 8; j++) pk.s[j] = tl[(lg + j) * 72 + d];
    *(uint4*)dst = pk.v;
    #pragma unroll
    for (int j = 0; j < 8; j++) pk.s[j] = tl[(lg + 8 + j) * 72 + d];
    *(uint4*)(dst + 8) = pk.v;
}

// ---------------- compacted-Q MFMA attention, fixed-shift softmax ----------------
// R14: K/V double-buffered (2-phase): attn2 runs 240 blocks < 256 CUs ->
// 1 block/CU, zero TLP; prefetch tile t+1 under compute of t.
__global__ __launch_bounds__(256) void attn2(
    const u16* __restrict__ qcomp, const u16* __restrict__ Kg,
    const u16* __restrict__ VTg, u16* __restrict__ ctxc)
{
    __shared__ u16 Qs[64 * 64];
    __shared__ u16 Ks[2][64 * 64];
    __shared__ u16 Vs[2][64 * 64];
    __shared__ u16 Ps[4 * 16 * 72];
    const int tid = threadIdx.x, wave = tid >> 6, lane = tid & 63;
    const int quad = lane >> 4, l15 = lane & 15;
    const int qb = blockIdx.x, h = blockIdx.y, b = blockIdx.z;
    const int q0 = qb * 64;

    {
        int s0 = wave * 64 + lane;
        int r = s0 >> 3, c = (s0 & 7) ^ (r & 7);
        gl16(qcomp + (size_t)(b * KPAD + q0 + r) * D_ + h * 64 + c * 8,
             &Qs[(wave * 64) * 8]);
        int s1 = s0 + 256;
        int r1 = s1 >> 3, c1 = (s1 & 7) ^ (r1 & 7);
        gl16(qcomp + (size_t)(b * KPAD + q0 + r1) * D_ + h * 64 + c1 * 8,
             &Qs[(256 + wave * 64) * 8]);
    }
    const u16 *kp0, *kp1, *vp0, *vp1;
    {
        int s0 = wave * 64 + lane;
        int r = s0 >> 3, c = (s0 & 7) ^ (r & 7);
        kp0 = Kg + (size_t)(b * L_ + r) * 1536 + h * 64 + c * 8;
        vp0 = VTg + (size_t)((b * H_ + h) * 64 + r) * L_ + c * 8;
        int s1 = s0 + 256;
        int r1 = s1 >> 3, c1 = (s1 & 7) ^ (r1 & 7);
        kp1 = Kg + (size_t)(b * L_ + r1) * 1536 + h * 64 + c1 * 8;
        vp1 = VTg + (size_t)((b * H_ + h) * 64 + r1) * L_ + c1 * 8;
    }
    // prologue: stage K/V tile 0 into buf 0 (alongside the Q stage above)
    gl16(kp0, &Ks[0][(wave * 64) * 8]);        kp0 += (size_t)64 * 1536;
    gl16(kp1, &Ks[0][(256 + wave * 64) * 8]);  kp1 += (size_t)64 * 1536;
    gl16(vp0, &Vs[0][(wave * 64) * 8]);        vp0 += 64;
    gl16(vp1, &Vs[0][(256 + wave * 64) * 8]);  vp1 += 64;
    wait_vm0();
    __syncthreads();
    bf16x8 qf0, qf1;
    {
        int row = wave * 16 + l15;
        qf0 = *(const bf16x8*)&Qs[(row * 8 + ((quad)     ^ (row & 7))) * 8];
        qf1 = *(const bf16x8*)&Qs[(row * 8 + ((4 + quad) ^ (row & 7))) * 8];
    }
    f32x4 accO[4]; float lp[4];
    #pragma unroll
    for (int i = 0; i < 4; i++) { accO[i] = 0.f; lp[i] = 0.f; }
    u16* Psw = Ps + wave * 16 * 72;

    for (int kt = 0; kt < L_; kt += 64) {
        const int buf = (kt >> 6) & 1;
        if (kt + 64 < L_) {         // prefetch tile t+1 into the other buffer
            gl16(kp0, &Ks[buf ^ 1][(wave * 64) * 8]);        kp0 += (size_t)64 * 1536;
            gl16(kp1, &Ks[buf ^ 1][(256 + wave * 64) * 8]);  kp1 += (size_t)64 * 1536;
            gl16(vp0, &Vs[buf ^ 1][(wave * 64) * 8]);        vp0 += 64;
            gl16(vp1, &Vs[buf ^ 1][(256 + wave * 64) * 8]);  vp1 += 64;
        }

        f32x4 accS[4];
        #pragma unroll
        for (int ni = 0; ni < 4; ni++) accS[ni] = 0.f;
        #pragma unroll
        for (int kk = 0; kk < 2; kk++) {
            const int kq = kk * 4 + quad;
            #pragma unroll
            for (int ni = 0; ni < 4; ni++) {
                int row = ni * 16 + l15;
                bf16x8 kf = *(const bf16x8*)&Ks[buf][(row * 8 + (kq ^ (row & 7))) * 8];
                accS[ni] = __builtin_amdgcn_mfma_f32_16x16x32_bf16(
                    kk ? qf1 : qf0, kf, accS[ni], 0, 0, 0);
            }
        }
        #pragma unroll
        for (int ni = 0; ni < 4; ni++) {
            #pragma unroll
            for (int r = 0; r < 4; r++) {
                float p = __expf(accS[ni][r]);
                lp[r] += p;
                Psw[(quad * 4 + r) * 72 + ni * 16 + l15] = f2bf(p);
            }
        }
        #pragma unroll
        for (int kk = 0; kk < 2; kk++) {
            bf16x8 pf = *(const bf16x8*)&Psw[l15 * 72 + kk * 32 + quad * 8];
            const int kq = kk * 4 + quad;
            #pragma unroll
            for (int ni = 0; ni < 4; ni++) {
                int row = ni * 16 + l15;
                bf16x8 vf = *(const bf16x8*)&Vs[buf][(row * 8 + (kq ^ (row & 7))) * 8];
                accO[ni] = __builtin_amdgcn_mfma_f32_16x16x32_bf16(pf, vf, accO[ni], 0, 0, 0);
            }
        }
        wait_vm0();                 // prefetch landed; barrier guards buf swap
        __syncthreads();
    }

    float invl[4];
    #pragma unroll
    for (int r = 0; r < 4; r++) {
        float s = lp[r];
        s += __shfl_xor(s, 1, 64); s += __shfl_xor(s, 2, 64);
        s += __shfl_xor(s, 4, 64); s += __shfl_xor(s, 8, 64);
        invl[r] = 1.0f / s;
    }
    #pragma unroll
    for (int ni = 0; ni < 4; ni++) {
        #pragma unroll
        for (int r = 0; r < 4; r++) {
            int ql = q0 + wave * 16 + quad * 4 + r;
            if (ql < KTOP)
                ctxc[(size_t)(b * KPAD + ql) * D_ + h * 64 + ni * 16 + l15] =
                    f2bf(accO[ni][r] * invl[r]);
        }
    }
}

// ---------------- launch ----------------
extern "C" void kernel_launch(void* const* d_in, const int* in_sizes, int n_in,
                              void* d_out, int out_size, void* d_ws, size_t ws_size,
                              hipStream_t stream)
{
    const float* x   = (const float*)d_in[0];
    const float* g1  = (const float*)d_in[1];
    const float* b1  = (const float*)d_in[2];
    const float* g2  = (const float*)d_in[3];
    const float* b2  = (const float*)d_in[4];
    const float* Wr  = (const float*)d_in[5];
    const float* br  = (const float*)d_in[6];
    const float* Wq  = (const float*)d_in[7];
    const float* bq  = (const float*)d_in[8];
    const float* Wk  = (const float*)d_in[9];
    const float* bk  = (const float*)d_in[10];
    const float* Wv  = (const float*)d_in[11];
    const float* bv  = (const float*)d_in[12];
    const float* Wo  = (const float*)d_in[13];
    const float* bo  = (const float*)d_in[14];
    const float* Wm  = (const float*)d_in[15];
    const float* bm  = (const float*)d_in[16];
    const float* W1  = (const float*)d_in[17];
    const float* bf1 = (const float*)d_in[18];
    const float* W2  = (const float*)d_in[19];
    const float* bf2 = (const float*)d_in[20];
    float* out = (float*)d_out;

    char* W = (char*)d_ws;
    u16* WqT  = (u16*)(W + 0);
    u16* WkvT = (u16*)(W + 1179648);
    u16* WoT  = (u16*)(W + 3538944);
    u16* WmT  = (u16*)(W + 4718592);
    u16* W1T  = (u16*)(W + 5898240);
    u16* W2T  = (u16*)(W + 10616832);
    float* scores  = (float*)(W + 15335424);
    unsigned* mask = (unsigned*)(W + 15368192);
    float* ssum    = (float*)(W + 15400960);
    float* pWm     = (float*)(W + 15413504);
    float* bkv     = (float*)(W + 15524096);
    float* bqs     = (float*)(W + 15530240);
    int* rowmap    = (int*)(W + 15533312);
    int* invmap    = (int*)(W + 15538432);
    u16* nb    = (u16*)(W + 15728640);
    u16* Y     = (u16*)(W + 28311552);
    u16* qcomp = (u16*)(W + 53477376);
    u16* ctxc  = (u16*)(W + 55443456);
    float* attnc = (float*)(W + 57409536);
    u16* VT    = (u16*)(W + 61341696);
    float* h   = (float*)(W + 28311552);
    u16* n2b   = (u16*)(W + 15728640);
    u16* mid   = (u16*)(W + 53477376);
    // R11: parts grew to 64 chunks x B x D fp32 (786KB) — aliases the qcomp
    // region, which is dead until the Q-projection (pooled_* run before it).
    float* parts = (float*)(W + 53477376);

    wconv_all<<<7489, 256, 0, stream>>>(Wq, Wk, Wv, Wo, Wm, W1, W2,
                                        WqT, WkvT, WoT, WmT, W1T, W2T,
                                        bq, bk, bv, bqs, bkv);

    const int NT = B_ * L_;
    ln_kernel<true><<<NT, 256, 0, stream>>>(x, g1, b1, Wr, br, nb, scores);
    topk_kernel<<<B_, 1024, 0, stream>>>(scores, mask, ssum, rowmap, invmap);
    pooled_part<<<dim3(64, B_), 256, 0, stream>>>(scores, nb, parts);
    pooled_wm<<<dim3(12, B_), 256, 0, stream>>>(parts, ssum, Wm, pWm);

    // dense KV projection -> Y [8192][1536]  (64 m x 12 n = 768 blocks)
    mfma_gemm<1, false, 128><<<768, 256, 0, stream>>>(nb, WkvT, bkv, Y, 1536, 768, 12,
        nullptr, nullptr, nullptr, nullptr, nullptr, nullptr, nullptr, nullptr);
    // gathered Q projection (scaled 1/8) -> qcomp [1280][768]  (20 m x 6 n = 120)
    mfma_gemm<1, true, 64><<<120, 256, 0, stream>>>(nb, WqT, bqs, qcomp, 768, 768, 6,
        nullptr, nullptr, nullptr, nullptr, nullptr, nullptr, rowmap, nullptr);
    // V transpose -> VT
    vtrans<<<dim3(32, H_, B_), 256, 0, stream>>>(Y + 768, VT, 1536);
    // compacted attention -> ctxc
    attn2<<<dim3(KPAD / 64, H_, B_), 256, 0, stream>>>(qcomp, Y, VT, ctxc);
    // attn_out (compact) = ctxc @ Wo + bo  (20 m x 6 n = 120)
    mfma_gemm<0, false, 64><<<120, 256, 0, stream>>>(ctxc, WoT, bo, attnc, 768, 768, 6,
        nullptr, nullptr, nullptr, nullptr, nullptr, nullptr, nullptr, nullptr);
    // h = x + where(mask, attnc[inv], normed@Wm + bm + s*pWm)  (128 m x 6 n = 768)
    mfma_gemm<3, false, 64><<<768, 256, 0, stream>>>(nb, WmT, bm, h, 768, 768, 6,
        x, mask, attnc, scores, pWm, nullptr, nullptr, invmap);
    // LN2 -> n2b
    ln_kernel<false><<<NT, 256, 0, stream>>>(h, g2, b2, nullptr, nullptr, n2b, nullptr);
    // FFN1 (TM=128, 64 m x 24 n = 1536 blocks)
    mfma_gemm<2, false, 128><<<1536, 256, 0, stream>>>(n2b, W1T, bf1, mid, 3072, 768, 24,
        nullptr, nullptr, nullptr, nullptr, nullptr, nullptr, nullptr, nullptr);
    // FFN2 (128 m x 6 n = 768)
    mfma_gemm<4, false, 64><<<768, 256, 0, stream>>>(mid, W2T, bf2, out, 768, 3072, 6,
        nullptr, nullptr, nullptr, nullptr, nullptr, h, nullptr, nullptr);
}